// Round 10
// baseline (214.948 us; speedup 1.0000x reference)
//
#include <hip/hip_runtime.h>
#include <stdint.h>

typedef _Float16 f16x8 __attribute__((ext_vector_type(8)));
typedef __bf16 bf16x8 __attribute__((ext_vector_type(8)));
typedef float f32x4 __attribute__((ext_vector_type(4)));

#define MFMA_F16(a,b,c) __builtin_amdgcn_mfma_f32_16x16x32_f16(a,b,c,0,0,0)
#define MFMA_BF16(a,b,c) __builtin_amdgcn_mfma_f32_16x16x32_bf16(a,b,c,0,0,0)
#define ALPHA 1.2011224087864498f   // sqrt(log2(e)); both operands scaled -> S in log2 domain

// ---------------- helpers ----------------
__device__ __forceinline__ uint32_t f2u(float x){ union{float f;uint32_t u;} c; c.f=x; return c.u; }
__device__ __forceinline__ float u2f(uint32_t u){ union{float f;uint32_t u;} c; c.u=u; return c.f; }

union HU8 { uint32_t u[4]; _Float16 h[8]; f16x8 v; };

// bf16 truncation split (fallback kernel)
__device__ __forceinline__ void split_pair(float x0, float x1, uint32_t& hp, uint32_t& lp){
  uint32_t u0=f2u(x0), u1=f2u(x1);
  uint32_t h0=u0&0xFFFF0000u, h1=u1&0xFFFF0000u;
  hp = (u0>>16) | h1;
  float l0 = x0 - u2f(h0), l1 = x1 - u2f(h1);
  lp = (f2u(l0)>>16) | (f2u(l1)&0xFFFF0000u);
}

// =====================================================================
// Pre-pass (fused K + m_k): ALPHA*x -> f16 RN plane
// =====================================================================
__global__ void kast_cvt3(const float* __restrict__ K_, const float* __restrict__ MK_,
                          uint4* __restrict__ khi, uint4* __restrict__ mkhi){
  int i = blockIdx.x*256 + threadIdx.x;     // 0..3145727
  const float* src; uint4* hi; int j;
  if (i < 2097152){ src = K_;  hi = khi;  j = i; }
  else            { src = MK_; hi = mkhi; j = i - 2097152; }
  const float4* in4 = (const float4*)src;
  float4 a = in4[(size_t)j*2], c = in4[(size_t)j*2+1];
  HU8 h;
  h.h[0]=(_Float16)(a.x*ALPHA); h.h[1]=(_Float16)(a.y*ALPHA);
  h.h[2]=(_Float16)(a.z*ALPHA); h.h[3]=(_Float16)(a.w*ALPHA);
  h.h[4]=(_Float16)(c.x*ALPHA); h.h[5]=(_Float16)(c.y*ALPHA);
  h.h[6]=(_Float16)(c.z*ALPHA); h.h[7]=(_Float16)(c.w*ALPHA);
  hi[j] = make_uint4(h.u[0],h.u[1],h.u[2],h.u[3]);
}

// =====================================================================
// v10 attn: NO K-LDS, NO per-tile barriers. 1344 blocks x 256 thr.
// Each wave loads its B-fragments straight from the f16 plane (L2) into
// registers (2-buffer prefetch), free-running waves hide latency.
// Softmax: log2 domain + defer-max (THR=24).
// =====================================================================
__launch_bounds__(256, 2)
__global__ void kast_attn10(const ushort* __restrict__ khi, const ushort* __restrict__ mkhi,
                            const float* __restrict__ V_, const float* __restrict__ MV_,
                            float* __restrict__ part) {
  __shared__ float vlds[1536];        // 512 keys x 3 f32 (only LDS use)

  // XCD-aware decode: slice s on XCD s%8
  const int bid = blockIdx.x;          // 0..1343
  const int xcd = bid & 7;
  const int idx = bid >> 3;            // 0..167
  const int grp = idx / 24;            // 0..6
  const int sub = idx - grp*24;        // 0..23
  const int s   = xcd + 8*grp;         // slice 0..55
  const int qb  = sub & 7;             // q-block 0..7
  const int ks  = sub >> 3;            // key-split 0..2
  const int b = s / 7, t = s % 7;

  const uint8_t* kh8; const float* vbase;
  if (ks < 2){
    size_t row0 = (size_t)((b*8 + t)*1024 + ks*512);
    kh8 = (const uint8_t*)khi + row0*512;
    vbase = V_ + row0*3;
  } else {
    size_t row0 = (size_t)((b*8 + t)*512);
    kh8 = (const uint8_t*)mkhi + row0*512;
    vbase = MV_ + row0*3;
  }

  const int tid = threadIdx.x;
  const int w = tid >> 6, l = tid & 63;
  const int lj = l & 15, lq = l >> 4;
  const int qrow0 = qb*128 + w*32;

  // ---- stage all V (512 x 3 f32) once; only barrier in the kernel ----
  for (int i = tid; i < 1536; i += 256) vlds[i] = vbase[i];

  // ---- Q fragments: b128 loads from pre-converted plane ----
  const uint8_t* q8 = (const uint8_t*)khi + (size_t)((b*8 + t + 1)*1024)*512;
  f16x8 qh[2][8];
#pragma unroll
  for (int rt=0; rt<2; rt++){
    const uint8_t* qr = q8 + (size_t)(qrow0 + rt*16 + lj)*512 + lq*16;
#pragma unroll
    for (int kc=0; kc<8; kc++)
      qh[rt][kc] = *(const f16x8*)(qr + kc*64);
  }
  __syncthreads();

  // per-lane online-softmax state (log2 domain, deferred max)
  float m[2][4], ssum[2][4], o[2][4][3];
#pragma unroll
  for (int rt=0;rt<2;rt++)
#pragma unroll
    for (int r=0;r<4;r++){
      m[rt][r]=-1e30f; ssum[rt][r]=0.f;
      o[rt][r][0]=0.f; o[rt][r][1]=0.f; o[rt][r][2]=0.f;
    }

  // per-lane K fragment base: row = ct*16 + lj, bytes kc*64 + lq*16
  const uint8_t* kp0 = kh8 + (size_t)(lj*512 + lq*16);   // ct=0 rows
  const uint8_t* kp1 = kp0 + 16*512;                     // ct=1 rows

  f16x8 ka[8], kb[8];
#pragma unroll
  for (int kc=0;kc<8;kc++) ka[kc] = *(const f16x8*)(kp0 + kc*64);   // tile 0, ct0

  for (int nt=0; nt<16; nt++){
    // issue ct1 loads for this tile
#pragma unroll
    for (int kc=0;kc<8;kc++) kb[kc] = *(const f16x8*)(kp1 + kc*64);

    f32x4 acc[2][2];
#pragma unroll
    for (int rt=0;rt<2;rt++){ acc[rt][0]=(f32x4){0,0,0,0}; acc[rt][1]=(f32x4){0,0,0,0}; }

    // ---- MFMA ct0 (ka resident since previous tile) ----
    __builtin_amdgcn_s_setprio(1);
#pragma unroll
    for (int kc=0;kc<8;kc++){
      acc[0][0] = MFMA_F16(qh[0][kc], ka[kc], acc[0][0]);
      acc[1][0] = MFMA_F16(qh[1][kc], ka[kc], acc[1][0]);
    }
    __builtin_amdgcn_s_setprio(0);

    // prefetch next tile's ct0 (in flight across softmax)
    kp0 += 16384; kp1 += 16384;
    if (nt < 15){
#pragma unroll
      for (int kc=0;kc<8;kc++) ka[kc] = *(const f16x8*)(kp0 + kc*64);
    }

    // ---- MFMA ct1 ----
    __builtin_amdgcn_s_setprio(1);
#pragma unroll
    for (int kc=0;kc<8;kc++){
      acc[0][1] = MFMA_F16(qh[0][kc], kb[kc], acc[0][1]);
      acc[1][1] = MFMA_F16(qh[1][kc], kb[kc], acc[1][1]);
    }
    __builtin_amdgcn_s_setprio(0);

    // ---- softmax, exp2 domain with deferred max ----
    float vv[2][3];
#pragma unroll
    for (int ct=0;ct<2;ct++){
      int c = (nt*32 + ct*16 + lj)*3;
      vv[ct][0]=vlds[c]; vv[ct][1]=vlds[c+1]; vv[ct][2]=vlds[c+2];
    }
    float pm[2][4];
    float need = -1e30f;
#pragma unroll
    for (int rt=0;rt<2;rt++)
#pragma unroll
      for (int r=0;r<4;r++){
        pm[rt][r] = fmaxf(acc[rt][0][r], acc[rt][1][r]);
        need = fmaxf(need, pm[rt][r] - m[rt][r]);
      }
    if (need > 24.f){      // rare (always tile 0): rescale to new reference
#pragma unroll
      for (int rt=0;rt<2;rt++)
#pragma unroll
        for (int r=0;r<4;r++){
          float mn = fmaxf(m[rt][r], pm[rt][r]);
          float sc = exp2f(m[rt][r] - mn);
          ssum[rt][r] *= sc;
          o[rt][r][0] *= sc; o[rt][r][1] *= sc; o[rt][r][2] *= sc;
          m[rt][r] = mn;
        }
    }
#pragma unroll
    for (int rt=0;rt<2;rt++)
#pragma unroll
      for (int r=0;r<4;r++){
        float p0 = exp2f(acc[rt][0][r] - m[rt][r]);
        float p1 = exp2f(acc[rt][1][r] - m[rt][r]);
        ssum[rt][r] += p0 + p1;
        o[rt][r][0] += p0*vv[0][0] + p1*vv[1][0];
        o[rt][r][1] += p0*vv[0][1] + p1*vv[1][1];
        o[rt][r][2] += p0*vv[0][2] + p1*vv[1][2];
      }
  } // nt

  // ---- merge 16 lanes (lj) per row, write partial (m,s,o) ----
#pragma unroll
  for (int rt=0;rt<2;rt++)
#pragma unroll
    for (int r=0;r<4;r++){
      float mm = m[rt][r];
      mm = fmaxf(mm, __shfl_xor(mm,1));
      mm = fmaxf(mm, __shfl_xor(mm,2));
      mm = fmaxf(mm, __shfl_xor(mm,4));
      mm = fmaxf(mm, __shfl_xor(mm,8));
      float f = exp2f(m[rt][r]-mm);
      float sl = ssum[rt][r]*f;
      float o0=o[rt][r][0]*f, o1=o[rt][r][1]*f, o2=o[rt][r][2]*f;
      sl += __shfl_xor(sl,1); sl += __shfl_xor(sl,2); sl += __shfl_xor(sl,4); sl += __shfl_xor(sl,8);
      o0 += __shfl_xor(o0,1); o0 += __shfl_xor(o0,2); o0 += __shfl_xor(o0,4); o0 += __shfl_xor(o0,8);
      o1 += __shfl_xor(o1,1); o1 += __shfl_xor(o1,2); o1 += __shfl_xor(o1,4); o1 += __shfl_xor(o1,8);
      o2 += __shfl_xor(o2,1); o2 += __shfl_xor(o2,2); o2 += __shfl_xor(o2,4); o2 += __shfl_xor(o2,8);
      if (lj == 0){
        int prow = qrow0 + rt*16 + lq*4 + r;
        float* pp = part + ((size_t)(s*3 + ks)*1024 + prow)*5;
        pp[0]=mm; pp[1]=sl; pp[2]=o0; pp[3]=o1; pp[4]=o2;
      }
    }
}

// merge 3 partials per q-row -> blended output (m,s are log2-domain)
__global__ void kast_merge(const float* __restrict__ part, float* __restrict__ OUT_){
  int r = blockIdx.x*256 + threadIdx.x;   // 0..57343
  if (r >= 56*1024) return;
  int s = r >> 10, row = r & 1023;
  const float* pa = part + ((size_t)(s*3+0)*1024 + row)*5;
  const float* pb = part + ((size_t)(s*3+1)*1024 + row)*5;
  const float* pm = part + ((size_t)(s*3+2)*1024 + row)*5;
  float ma=pa[0], sa=pa[1], mb=pb[0], sb=pb[1];
  float M = fmaxf(ma,mb);
  float ea = exp2f(ma-M), eb = exp2f(mb-M);
  float w1 = 0.8f / (sa*ea + sb*eb);
  float w2 = 0.2f / pm[1];
  float* op = OUT_ + (size_t)(s*1024 + row)*3;
  op[0] = (pa[2]*ea + pb[2]*eb)*w1 + pm[2]*w2;
  op[1] = (pa[3]*ea + pb[3]*eb)*w1 + pm[3]*w2;
  op[2] = (pa[4]*ea + pb[4]*eb)*w1 + pm[4]*w2;
}

// =====================================================================
// Fallback (round-2 passing kernel) if ws too small
// =====================================================================
__launch_bounds__(256, 2)
__global__ void kast_attn_fb(const float* __restrict__ K_, const float* __restrict__ V_,
                             const float* __restrict__ MK_, const float* __restrict__ MV_,
                             float* __restrict__ OUT_) {
  __shared__ char KhB[64*512];
  __shared__ char KlB[64*512];
  __shared__ float vlds[192];

  const int bid = blockIdx.x;
  const int s  = ((bid>>6)<<3) | (bid & 7);
  const int qb = (bid>>3) & 7;
  const int b = s / 7, t = s % 7;
  const float* qptr = K_ + (size_t)((b*8 + t + 1) * 1024) * 256;
  const float* k1   = K_ + (size_t)((b*8 + t) * 1024) * 256;
  const float* v1   = V_ + (size_t)((b*8 + t) * 1024) * 3;
  const float* k2   = MK_ + (size_t)((b*8 + t) * 512) * 256;
  const float* v2   = MV_ + (size_t)((b*8 + t) * 512) * 3;
  float* outp = OUT_ + (size_t)((b*7 + t) * 1024) * 3;

  const int tid = threadIdx.x;
  const int w = tid >> 6, l = tid & 63;
  const int lj = l & 15, lq = l >> 4;
  const int qrow0 = qb*128 + w*32;

  bf16x8 qh[2][8], ql[2][8];
#pragma unroll
  for (int rt=0; rt<2; rt++){
    const float* qr = qptr + (size_t)(qrow0 + rt*16 + lj)*256 + lq*8;
#pragma unroll
    for (int kc=0; kc<8; kc++){
      float4 a = *(const float4*)(qr + kc*32);
      float4 c = *(const float4*)(qr + kc*32 + 4);
      union { uint32_t d[4]; bf16x8 v; } hh, ll;
      split_pair(a.x, a.y, hh.d[0], ll.d[0]);
      split_pair(a.z, a.w, hh.d[1], ll.d[1]);
      split_pair(c.x, c.y, hh.d[2], ll.d[2]);
      split_pair(c.z, c.w, hh.d[3], ll.d[3]);
      qh[rt][kc]=hh.v; ql[rt][kc]=ll.v;
    }
  }

  for (int ph=0; ph<2; ph++){
    const float* ks = ph ? k2 : k1;
    const float* vs = ph ? v2 : v1;
    const int ntiles = ph ? 8 : 16;
    float m[2][4], ssum[2][4], o[2][4][3];
#pragma unroll
    for (int rt=0;rt<2;rt++)
#pragma unroll
      for (int r=0;r<4;r++){
        m[rt][r]=-1e30f; ssum[rt][r]=0.f;
        o[rt][r][0]=0.f; o[rt][r][1]=0.f; o[rt][r][2]=0.f;
      }

    for (int nt=0; nt<ntiles; nt++){
      __syncthreads();
      const float* kt = ks + (size_t)nt*64*256;
#pragma unroll 4
      for (int i=0;i<16;i++){
        int f4i = tid + i*256;
        int row = f4i >> 6;
        int col4 = f4i & 63;
        float4 x = *(const float4*)(kt + row*256 + col4*4);
        uint32_t hp0,lp0,hp1,lp1;
        split_pair(x.x,x.y,hp0,lp0);
        split_pair(x.z,x.w,hp1,lp1);
        int boff = row*512 + ((col4*8) ^ ((row&7)<<4));
        *(uint2*)(KhB + boff) = make_uint2(hp0,hp1);
        *(uint2*)(KlB + boff) = make_uint2(lp0,lp1);
      }
      if (tid < 192) vlds[tid] = vs[nt*192 + tid];
      __syncthreads();

      f32x4 acc[2][4];
#pragma unroll
      for (int rt=0;rt<2;rt++)
#pragma unroll
        for (int ct=0;ct<4;ct++)
          acc[rt][ct] = (f32x4){0.f,0.f,0.f,0.f};

      const int sx = (l&7)<<4;
#pragma unroll
      for (int ct=0;ct<4;ct++){
        const char* rbh = KhB + (ct*16 + lj)*512;
        const char* rbl = KlB + (ct*16 + lj)*512;
#pragma unroll
        for (int kc=0;kc<8;kc++){
          int bo = (kc*64 + (lq<<4)) ^ sx;
          bf16x8 bh = *(const bf16x8*)(rbh + bo);
          bf16x8 bl = *(const bf16x8*)(rbl + bo);
          acc[0][ct] = MFMA_BF16(qh[0][kc], bh, acc[0][ct]);
          acc[1][ct] = MFMA_BF16(qh[1][kc], bh, acc[1][ct]);
          acc[0][ct] = MFMA_BF16(qh[0][kc], bl, acc[0][ct]);
          acc[1][ct] = MFMA_BF16(qh[1][kc], bl, acc[1][ct]);
          acc[0][ct] = MFMA_BF16(ql[0][kc], bh, acc[0][ct]);
          acc[1][ct] = MFMA_BF16(ql[1][kc], bh, acc[1][ct]);
        }
      }

      float vv[4][3];
#pragma unroll
      for (int ct=0;ct<4;ct++){
        int c = (ct*16 + lj)*3;
        vv[ct][0]=vlds[c]; vv[ct][1]=vlds[c+1]; vv[ct][2]=vlds[c+2];
      }
#pragma unroll
      for (int rt=0;rt<2;rt++)
#pragma unroll
        for (int r=0;r<4;r++){
          float s0=acc[rt][0][r], s1=acc[rt][1][r], s2=acc[rt][2][r], s3=acc[rt][3][r];
          float tmax = fmaxf(fmaxf(s0,s1),fmaxf(s2,s3));
          float mo = m[rt][r];
          float mn = fmaxf(mo, tmax);
          float sc = __expf(mo - mn);
          float p0=__expf(s0-mn), p1=__expf(s1-mn), p2=__expf(s2-mn), p3=__expf(s3-mn);
          ssum[rt][r] = ssum[rt][r]*sc + ((p0+p1)+(p2+p3));
          o[rt][r][0] = o[rt][r][0]*sc + (p0*vv[0][0]+p1*vv[1][0]) + (p2*vv[2][0]+p3*vv[3][0]);
          o[rt][r][1] = o[rt][r][1]*sc + (p0*vv[0][1]+p1*vv[1][1]) + (p2*vv[2][1]+p3*vv[3][1]);
          o[rt][r][2] = o[rt][r][2]*sc + (p0*vv[0][2]+p1*vv[1][2]) + (p2*vv[2][2]+p3*vv[3][2]);
          m[rt][r]=mn;
        }
    }

    const float coef = ph ? 0.2f : 0.8f;
#pragma unroll
    for (int rt=0;rt<2;rt++)
#pragma unroll
      for (int r=0;r<4;r++){
        float mm = m[rt][r];
        mm = fmaxf(mm, __shfl_xor(mm,1));
        mm = fmaxf(mm, __shfl_xor(mm,2));
        mm = fmaxf(mm, __shfl_xor(mm,4));
        mm = fmaxf(mm, __shfl_xor(mm,8));
        float f = __expf(m[rt][r]-mm);
        float sl = ssum[rt][r]*f;
        float o0=o[rt][r][0]*f, o1=o[rt][r][1]*f, o2=o[rt][r][2]*f;
        sl += __shfl_xor(sl,1); sl += __shfl_xor(sl,2); sl += __shfl_xor(sl,4); sl += __shfl_xor(sl,8);
        o0 += __shfl_xor(o0,1); o0 += __shfl_xor(o0,2); o0 += __shfl_xor(o0,4); o0 += __shfl_xor(o0,8);
        o1 += __shfl_xor(o1,1); o1 += __shfl_xor(o1,2); o1 += __shfl_xor(o1,4); o1 += __shfl_xor(o1,8);
        o2 += __shfl_xor(o2,1); o2 += __shfl_xor(o2,2); o2 += __shfl_xor(o2,4); o2 += __shfl_xor(o2,8);
        if (lj == 0){
          int row = qrow0 + rt*16 + lq*4 + r;
          float* op = outp + (size_t)row*3;
          float invs = coef / sl;
          if (ph==0){ op[0]=o0*invs; op[1]=o1*invs; op[2]=o2*invs; }
          else      { op[0]+=o0*invs; op[1]+=o1*invs; op[2]+=o2*invs; }
        }
      }
  }
}

// ground truth = v[:,1:] (second output, exact copy)
__global__ void kast_gt(const float* __restrict__ V_, float* __restrict__ OUT_){
  int s = blockIdx.x; int b = s/7, t = s%7;
  const float4* src = (const float4*)(V_ + (size_t)(b*8+t+1)*3072);
  float4* dst = (float4*)(OUT_ + 172032 + (size_t)s*3072);
  for (int i=threadIdx.x; i<768; i+=256) dst[i] = src[i];
}

extern "C" void kernel_launch(void* const* d_in, const int* in_sizes, int n_in,
                              void* d_out, int out_size, void* d_ws, size_t ws_size,
                              hipStream_t stream) {
  (void)in_sizes; (void)n_in; (void)out_size;
  const float* K_  = (const float*)d_in[0];
  const float* V_  = (const float*)d_in[1];
  const float* MK_ = (const float*)d_in[2];
  const float* MV_ = (const float*)d_in[3];
  float* out = (float*)d_out;

  // ws layout (bytes): khi 33.55M | mkhi 16.78M | partials 3.44M
  const size_t NEED = 53772288;
  if (ws_size >= NEED){
    uint8_t* w8 = (uint8_t*)d_ws;
    ushort* khi  = (ushort*)(w8);
    ushort* mkhi = (ushort*)(w8 + 33554432);
    float*  part = (float*)(w8 + 50331648);
    hipLaunchKernelGGL(kast_cvt3, dim3(12288), dim3(256), 0, stream, K_, MK_,
                       (uint4*)khi, (uint4*)mkhi);
    hipLaunchKernelGGL(kast_attn10, dim3(1344), dim3(256), 0, stream, khi, mkhi, V_, MV_, part);
    hipLaunchKernelGGL(kast_merge, dim3(224),  dim3(256), 0, stream, part, out);
  } else {
    hipLaunchKernelGGL(kast_attn_fb, dim3(448), dim3(256), 0, stream, K_, V_, MK_, MV_, out);
  }
  hipLaunchKernelGGL(kast_gt, dim3(56), dim3(256), 0, stream, V_, out);
}

// Round 11
// 141.395 us; speedup vs baseline: 1.5202x; 1.5202x over previous
//
#include <hip/hip_runtime.h>
#include <stdint.h>

typedef _Float16 f16x8 __attribute__((ext_vector_type(8)));
typedef __bf16 bf16x8 __attribute__((ext_vector_type(8)));
typedef float f32x4 __attribute__((ext_vector_type(4)));

#define MFMA_F16(a,b,c) __builtin_amdgcn_mfma_f32_16x16x32_f16(a,b,c,0,0,0)
#define MFMA_BF16(a,b,c) __builtin_amdgcn_mfma_f32_16x16x32_bf16(a,b,c,0,0,0)
#define ALPHA 1.2011224087864498f   // sqrt(log2(e)); both operands scaled -> S in log2 domain

// ---------------- helpers ----------------
__device__ __forceinline__ uint32_t f2u(float x){ union{float f;uint32_t u;} c; c.f=x; return c.u; }
__device__ __forceinline__ float u2f(uint32_t u){ union{float f;uint32_t u;} c; c.u=u; return c.f; }

union HU8 { uint32_t u[4]; _Float16 h[8]; f16x8 v; };

// bf16 truncation split (fallback kernel)
__device__ __forceinline__ void split_pair(float x0, float x1, uint32_t& hp, uint32_t& lp){
  uint32_t u0=f2u(x0), u1=f2u(x1);
  uint32_t h0=u0&0xFFFF0000u, h1=u1&0xFFFF0000u;
  hp = (u0>>16) | h1;
  float l0 = x0 - u2f(h0), l1 = x1 - u2f(h1);
  lp = (f2u(l0)>>16) | (f2u(l1)&0xFFFF0000u);
}

// async global->LDS, 16 bytes per lane. LDS dest = wave-uniform base + lane*16.
__device__ __forceinline__ void glds16(const void* g, void* l){
  __builtin_amdgcn_global_load_lds(
      (const __attribute__((address_space(1))) uint32_t*)(uintptr_t)g,
      (__attribute__((address_space(3))) uint32_t*)(uint32_t)(uintptr_t)l,
      16, 0, 0);
}

// =====================================================================
// Pre-pass (fused K + m_k): ALPHA*x -> f16 RN plane
// =====================================================================
__global__ void kast_cvt3(const float* __restrict__ K_, const float* __restrict__ MK_,
                          uint4* __restrict__ khi, uint4* __restrict__ mkhi){
  int i = blockIdx.x*256 + threadIdx.x;     // 0..3145727
  const float* src; uint4* hi; int j;
  if (i < 2097152){ src = K_;  hi = khi;  j = i; }
  else            { src = MK_; hi = mkhi; j = i - 2097152; }
  const float4* in4 = (const float4*)src;
  float4 a = in4[(size_t)j*2], c = in4[(size_t)j*2+1];
  HU8 h;
  h.h[0]=(_Float16)(a.x*ALPHA); h.h[1]=(_Float16)(a.y*ALPHA);
  h.h[2]=(_Float16)(a.z*ALPHA); h.h[3]=(_Float16)(a.w*ALPHA);
  h.h[4]=(_Float16)(c.x*ALPHA); h.h[5]=(_Float16)(c.y*ALPHA);
  h.h[6]=(_Float16)(c.z*ALPHA); h.h[7]=(_Float16)(c.w*ALPHA);
  hi[j] = make_uint4(h.u[0],h.u[1],h.u[2],h.u[3]);
}

// =====================================================================
// v11 attn: v9 structure with 512-thread blocks (8 waves share the
// 38.9KB LDS tile -> 16 waves/CU) + defer-max softmax. Grid 672 =
// 56 slices x 4 qb x 3 key-splits; each block: 256 q-rows x 512 keys.
// NO launch-bounds forcing (r4/r8: forcing -> spills).
// =====================================================================
__launch_bounds__(512, 1)
__global__ void kast_attn11(const ushort* __restrict__ khi, const ushort* __restrict__ mkhi,
                            const float* __restrict__ V_, const float* __restrict__ MV_,
                            float* __restrict__ part) {
  __shared__ uint8_t KB[2][16384];    // [buf][32 keys x 256 f16], XOR-swizzled granules
  __shared__ float vlds[1536];        // 512 keys x 3 f32

  // XCD-aware decode: slice s on XCD s%8; its 12 blocks share that L2
  const int bid = blockIdx.x;          // 0..671
  const int xcd = bid & 7;
  const int idx = bid >> 3;            // 0..83
  const int grp = idx / 12;            // 0..6
  const int sub = idx - grp*12;        // 0..11
  const int s   = xcd + 8*grp;         // slice 0..55
  const int qbB = sub & 3;             // q-block 0..3 (256 rows)
  const int ks  = sub >> 2;            // key-split 0..2
  const int b = s / 7, t = s % 7;

  const uint8_t* kh8; const float* vbase;
  if (ks < 2){
    size_t row0 = (size_t)((b*8 + t)*1024 + ks*512);
    kh8 = (const uint8_t*)khi + row0*512;
    vbase = V_ + row0*3;
  } else {
    size_t row0 = (size_t)((b*8 + t)*512);
    kh8 = (const uint8_t*)mkhi + row0*512;
    vbase = MV_ + row0*3;
  }

  const int tid = threadIdx.x;
  const int w = tid >> 6, l = tid & 63;     // w = 0..7
  const int lj = l & 15, lq = l >> 4;
  const int qrow0 = qbB*256 + w*32;

  // ---- stage all V (512 x 3 f32) once ----
  for (int i = tid; i < 1536; i += 512) vlds[i] = vbase[i];

  // ---- Q fragments: b128 loads from pre-converted plane ----
  const uint8_t* q8 = (const uint8_t*)khi + (size_t)((b*8 + t + 1)*1024)*512;
  f16x8 qh[2][8];
#pragma unroll
  for (int rt=0; rt<2; rt++){
    const uint8_t* qr = q8 + (size_t)(qrow0 + rt*16 + lj)*512 + lq*16;
#pragma unroll
    for (int kc=0; kc<8; kc++)
      qh[rt][kc] = *(const f16x8*)(qr + kc*64);
  }

  // per-lane online-softmax state (log2 domain, deferred max)
  float m[2][4], ssum[2][4], o[2][4][3];
#pragma unroll
  for (int rt=0;rt<2;rt++)
#pragma unroll
    for (int r=0;r<4;r++){
      m[rt][r]=-1e30f; ssum[rt][r]=0.f;
      o[rt][r][0]=0.f; o[rt][r][1]=0.f; o[rt][r][2]=0.f;
    }

  // DMA: 8 waves x 4 rows/tile = 2 glds16 each. per-lane source row =
  // w*4 + i*2 + (l>>5); granule sg = l&31 pre-swizzled with g^(row&7).
  const int sg = l & 31;
  const int rsub = l >> 5;

  #define ISSUE_TILE(NT, P) do{                                              \
    _Pragma("unroll")                                                        \
    for (int i_=0;i_<2;i_++){                                                \
      int lrow_ = (w<<2) + (i_<<1) + rsub;                                   \
      size_t soff_ = (size_t)((NT)*32 + lrow_)*512 + (size_t)((sg ^ (lrow_&7))<<4); \
      uint32_t dbase_ = ((w<<2) + (i_<<1))*512;                              \
      glds16(kh8 + soff_, &KB[(P)][dbase_]);                                 \
    } }while(0)

  // prologue: tile 0 -> buf 0; full sync also covers V-staging ds_writes
  ISSUE_TILE(0, 0);
  __syncthreads();

  for (int nt=0; nt<16; nt++){
    const int cur = nt & 1;
    if (nt < 15){
      ISSUE_TILE(nt+1, cur^1);
      asm volatile("s_waitcnt vmcnt(2)" ::: "memory");  // cur tile's 2 DMA done; next 2 in flight
    } else {
      asm volatile("s_waitcnt vmcnt(0)" ::: "memory");
    }
    asm volatile("s_barrier" ::: "memory");             // all waves: buf[cur] ready

    // ---- MFMA: S = Qh*Kh (log2 domain) ----
    f32x4 acc[2][2];
#pragma unroll
    for (int rt=0;rt<2;rt++){ acc[rt][0]=(f32x4){0,0,0,0}; acc[rt][1]=(f32x4){0,0,0,0}; }

    const int sx = (l&7)<<4;
#pragma unroll
    for (int ct=0;ct<2;ct++){
      const uint8_t* rb = &KB[cur][(ct*16 + lj)*512];
#pragma unroll
      for (int kc=0;kc<8;kc++){
        int bo = (kc*64 + (lq<<4)) ^ sx;
        f16x8 bh = *(const f16x8*)(rb + bo);
        acc[0][ct] = MFMA_F16(qh[0][kc], bh, acc[0][ct]);
        acc[1][ct] = MFMA_F16(qh[1][kc], bh, acc[1][ct]);
      }
    }

    // ---- softmax, exp2 domain with deferred max (THR=24) + PV ----
    float vv[2][3];
#pragma unroll
    for (int ct=0;ct<2;ct++){
      int c = (nt*32 + ct*16 + lj)*3;
      vv[ct][0]=vlds[c]; vv[ct][1]=vlds[c+1]; vv[ct][2]=vlds[c+2];
    }
    float pm[2][4];
    float need = -1e30f;
#pragma unroll
    for (int rt=0;rt<2;rt++)
#pragma unroll
      for (int r=0;r<4;r++){
        pm[rt][r] = fmaxf(acc[rt][0][r], acc[rt][1][r]);
        need = fmaxf(need, pm[rt][r] - m[rt][r]);
      }
    if (need > 24.f){      // rare after tile 0: rescale to new reference
#pragma unroll
      for (int rt=0;rt<2;rt++)
#pragma unroll
        for (int r=0;r<4;r++){
          float mn = fmaxf(m[rt][r], pm[rt][r]);
          float sc = exp2f(m[rt][r] - mn);
          ssum[rt][r] *= sc;
          o[rt][r][0] *= sc; o[rt][r][1] *= sc; o[rt][r][2] *= sc;
          m[rt][r] = mn;
        }
    }
#pragma unroll
    for (int rt=0;rt<2;rt++)
#pragma unroll
      for (int r=0;r<4;r++){
        float p0 = exp2f(acc[rt][0][r] - m[rt][r]);
        float p1 = exp2f(acc[rt][1][r] - m[rt][r]);
        ssum[rt][r] += p0 + p1;
        o[rt][r][0] += p0*vv[0][0] + p1*vv[1][0];
        o[rt][r][1] += p0*vv[0][1] + p1*vv[1][1];
        o[rt][r][2] += p0*vv[0][2] + p1*vv[1][2];
      }

    asm volatile("s_barrier" ::: "memory");             // all waves done reading buf[cur]
  } // nt

  // ---- merge 16 lanes (lj) per row, write partial (m,s,o) ----
#pragma unroll
  for (int rt=0;rt<2;rt++)
#pragma unroll
    for (int r=0;r<4;r++){
      float mm = m[rt][r];
      mm = fmaxf(mm, __shfl_xor(mm,1));
      mm = fmaxf(mm, __shfl_xor(mm,2));
      mm = fmaxf(mm, __shfl_xor(mm,4));
      mm = fmaxf(mm, __shfl_xor(mm,8));
      float f = exp2f(m[rt][r]-mm);
      float sl = ssum[rt][r]*f;
      float o0=o[rt][r][0]*f, o1=o[rt][r][1]*f, o2=o[rt][r][2]*f;
      sl += __shfl_xor(sl,1); sl += __shfl_xor(sl,2); sl += __shfl_xor(sl,4); sl += __shfl_xor(sl,8);
      o0 += __shfl_xor(o0,1); o0 += __shfl_xor(o0,2); o0 += __shfl_xor(o0,4); o0 += __shfl_xor(o0,8);
      o1 += __shfl_xor(o1,1); o1 += __shfl_xor(o1,2); o1 += __shfl_xor(o1,4); o1 += __shfl_xor(o1,8);
      o2 += __shfl_xor(o2,1); o2 += __shfl_xor(o2,2); o2 += __shfl_xor(o2,4); o2 += __shfl_xor(o2,8);
      if (lj == 0){
        int prow = qrow0 + rt*16 + lq*4 + r;
        float* pp = part + ((size_t)(s*3 + ks)*1024 + prow)*5;
        pp[0]=mm; pp[1]=sl; pp[2]=o0; pp[3]=o1; pp[4]=o2;
      }
    }
  #undef ISSUE_TILE
}

// merge 3 partials per q-row -> blended output (m,s are log2-domain)
__global__ void kast_merge(const float* __restrict__ part, float* __restrict__ OUT_){
  int r = blockIdx.x*256 + threadIdx.x;   // 0..57343
  if (r >= 56*1024) return;
  int s = r >> 10, row = r & 1023;
  const float* pa = part + ((size_t)(s*3+0)*1024 + row)*5;
  const float* pb = part + ((size_t)(s*3+1)*1024 + row)*5;
  const float* pm = part + ((size_t)(s*3+2)*1024 + row)*5;
  float ma=pa[0], sa=pa[1], mb=pb[0], sb=pb[1];
  float M = fmaxf(ma,mb);
  float ea = exp2f(ma-M), eb = exp2f(mb-M);
  float w1 = 0.8f / (sa*ea + sb*eb);
  float w2 = 0.2f / pm[1];
  float* op = OUT_ + (size_t)(s*1024 + row)*3;
  op[0] = (pa[2]*ea + pb[2]*eb)*w1 + pm[2]*w2;
  op[1] = (pa[3]*ea + pb[3]*eb)*w1 + pm[3]*w2;
  op[2] = (pa[4]*ea + pb[4]*eb)*w1 + pm[4]*w2;
}

// =====================================================================
// Fallback (round-2 passing kernel) if ws too small
// =====================================================================
__launch_bounds__(256, 2)
__global__ void kast_attn_fb(const float* __restrict__ K_, const float* __restrict__ V_,
                             const float* __restrict__ MK_, const float* __restrict__ MV_,
                             float* __restrict__ OUT_) {
  __shared__ char KhB[64*512];
  __shared__ char KlB[64*512];
  __shared__ float vlds[192];

  const int bid = blockIdx.x;
  const int s  = ((bid>>6)<<3) | (bid & 7);
  const int qb = (bid>>3) & 7;
  const int b = s / 7, t = s % 7;
  const float* qptr = K_ + (size_t)((b*8 + t + 1) * 1024) * 256;
  const float* k1   = K_ + (size_t)((b*8 + t) * 1024) * 256;
  const float* v1   = V_ + (size_t)((b*8 + t) * 1024) * 3;
  const float* k2   = MK_ + (size_t)((b*8 + t) * 512) * 256;
  const float* v2   = MV_ + (size_t)((b*8 + t) * 512) * 3;
  float* outp = OUT_ + (size_t)((b*7 + t) * 1024) * 3;

  const int tid = threadIdx.x;
  const int w = tid >> 6, l = tid & 63;
  const int lj = l & 15, lq = l >> 4;
  const int qrow0 = qb*128 + w*32;

  bf16x8 qh[2][8], ql[2][8];
#pragma unroll
  for (int rt=0; rt<2; rt++){
    const float* qr = qptr + (size_t)(qrow0 + rt*16 + lj)*256 + lq*8;
#pragma unroll
    for (int kc=0; kc<8; kc++){
      float4 a = *(const float4*)(qr + kc*32);
      float4 c = *(const float4*)(qr + kc*32 + 4);
      union { uint32_t d[4]; bf16x8 v; } hh, ll;
      split_pair(a.x, a.y, hh.d[0], ll.d[0]);
      split_pair(a.z, a.w, hh.d[1], ll.d[1]);
      split_pair(c.x, c.y, hh.d[2], ll.d[2]);
      split_pair(c.z, c.w, hh.d[3], ll.d[3]);
      qh[rt][kc]=hh.v; ql[rt][kc]=ll.v;
    }
  }

  for (int ph=0; ph<2; ph++){
    const float* ks = ph ? k2 : k1;
    const float* vs = ph ? v2 : v1;
    const int ntiles = ph ? 8 : 16;
    float m[2][4], ssum[2][4], o[2][4][3];
#pragma unroll
    for (int rt=0;rt<2;rt++)
#pragma unroll
      for (int r=0;r<4;r++){
        m[rt][r]=-1e30f; ssum[rt][r]=0.f;
        o[rt][r][0]=0.f; o[rt][r][1]=0.f; o[rt][r][2]=0.f;
      }

    for (int nt=0; nt<ntiles; nt++){
      __syncthreads();
      const float* kt = ks + (size_t)nt*64*256;
#pragma unroll 4
      for (int i=0;i<16;i++){
        int f4i = tid + i*256;
        int row = f4i >> 6;
        int col4 = f4i & 63;
        float4 x = *(const float4*)(kt + row*256 + col4*4);
        uint32_t hp0,lp0,hp1,lp1;
        split_pair(x.x,x.y,hp0,lp0);
        split_pair(x.z,x.w,hp1,lp1);
        int boff = row*512 + ((col4*8) ^ ((row&7)<<4));
        *(uint2*)(KhB + boff) = make_uint2(hp0,hp1);
        *(uint2*)(KlB + boff) = make_uint2(lp0,lp1);
      }
      if (tid < 192) vlds[tid] = vs[nt*192 + tid];
      __syncthreads();

      f32x4 acc[2][4];
#pragma unroll
      for (int rt=0;rt<2;rt++)
#pragma unroll
        for (int ct=0;ct<4;ct++)
          acc[rt][ct] = (f32x4){0.f,0.f,0.f,0.f};

      const int sx = (l&7)<<4;
#pragma unroll
      for (int ct=0;ct<4;ct++){
        const char* rbh = KhB + (ct*16 + lj)*512;
        const char* rbl = KlB + (ct*16 + lj)*512;
#pragma unroll
        for (int kc=0;kc<8;kc++){
          int bo = (kc*64 + (lq<<4)) ^ sx;
          bf16x8 bh = *(const bf16x8*)(rbh + bo);
          bf16x8 bl = *(const bf16x8*)(rbl + bo);
          acc[0][ct] = MFMA_BF16(qh[0][kc], bh, acc[0][ct]);
          acc[1][ct] = MFMA_BF16(qh[1][kc], bh, acc[1][ct]);
          acc[0][ct] = MFMA_BF16(qh[0][kc], bl, acc[0][ct]);
          acc[1][ct] = MFMA_BF16(qh[1][kc], bl, acc[1][ct]);
          acc[0][ct] = MFMA_BF16(ql[0][kc], bh, acc[0][ct]);
          acc[1][ct] = MFMA_BF16(ql[1][kc], bh, acc[1][ct]);
        }
      }

      float vv[4][3];
#pragma unroll
      for (int ct=0;ct<4;ct++){
        int c = (ct*16 + lj)*3;
        vv[ct][0]=vlds[c]; vv[ct][1]=vlds[c+1]; vv[ct][2]=vlds[c+2];
      }
#pragma unroll
      for (int rt=0;rt<2;rt++)
#pragma unroll
        for (int r=0;r<4;r++){
          float s0=acc[rt][0][r], s1=acc[rt][1][r], s2=acc[rt][2][r], s3=acc[rt][3][r];
          float tmax = fmaxf(fmaxf(s0,s1),fmaxf(s2,s3));
          float mo = m[rt][r];
          float mn = fmaxf(mo, tmax);
          float sc = __expf(mo - mn);
          float p0=__expf(s0-mn), p1=__expf(s1-mn), p2=__expf(s2-mn), p3=__expf(s3-mn);
          ssum[rt][r] = ssum[rt][r]*sc + ((p0+p1)+(p2+p3));
          o[rt][r][0] = o[rt][r][0]*sc + (p0*vv[0][0]+p1*vv[1][0]) + (p2*vv[2][0]+p3*vv[3][0]);
          o[rt][r][1] = o[rt][r][1]*sc + (p0*vv[0][1]+p1*vv[1][1]) + (p2*vv[2][1]+p3*vv[3][1]);
          o[rt][r][2] = o[rt][r][2]*sc + (p0*vv[0][2]+p1*vv[1][2]) + (p2*vv[2][2]+p3*vv[3][2]);
          m[rt][r]=mn;
        }
    }

    const float coef = ph ? 0.2f : 0.8f;
#pragma unroll
    for (int rt=0;rt<2;rt++)
#pragma unroll
      for (int r=0;r<4;r++){
        float mm = m[rt][r];
        mm = fmaxf(mm, __shfl_xor(mm,1));
        mm = fmaxf(mm, __shfl_xor(mm,2));
        mm = fmaxf(mm, __shfl_xor(mm,4));
        mm = fmaxf(mm, __shfl_xor(mm,8));
        float f = __expf(m[rt][r]-mm);
        float sl = ssum[rt][r]*f;
        float o0=o[rt][r][0]*f, o1=o[rt][r][1]*f, o2=o[rt][r][2]*f;
        sl += __shfl_xor(sl,1); sl += __shfl_xor(sl,2); sl += __shfl_xor(sl,4); sl += __shfl_xor(sl,8);
        o0 += __shfl_xor(o0,1); o0 += __shfl_xor(o0,2); o0 += __shfl_xor(o0,4); o0 += __shfl_xor(o0,8);
        o1 += __shfl_xor(o1,1); o1 += __shfl_xor(o1,2); o1 += __shfl_xor(o1,4); o1 += __shfl_xor(o1,8);
        o2 += __shfl_xor(o2,1); o2 += __shfl_xor(o2,2); o2 += __shfl_xor(o2,4); o2 += __shfl_xor(o2,8);
        if (lj == 0){
          int row = qrow0 + rt*16 + lq*4 + r;
          float* op = outp + (size_t)row*3;
          float invs = coef / sl;
          if (ph==0){ op[0]=o0*invs; op[1]=o1*invs; op[2]=o2*invs; }
          else      { op[0]+=o0*invs; op[1]+=o1*invs; op[2]+=o2*invs; }
        }
      }
  }
}

// ground truth = v[:,1:] (second output, exact copy)
__global__ void kast_gt(const float* __restrict__ V_, float* __restrict__ OUT_){
  int s = blockIdx.x; int b = s/7, t = s%7;
  const float4* src = (const float4*)(V_ + (size_t)(b*8+t+1)*3072);
  float4* dst = (float4*)(OUT_ + 172032 + (size_t)s*3072);
  for (int i=threadIdx.x; i<768; i+=256) dst[i] = src[i];
}

extern "C" void kernel_launch(void* const* d_in, const int* in_sizes, int n_in,
                              void* d_out, int out_size, void* d_ws, size_t ws_size,
                              hipStream_t stream) {
  (void)in_sizes; (void)n_in; (void)out_size;
  const float* K_  = (const float*)d_in[0];
  const float* V_  = (const float*)d_in[1];
  const float* MK_ = (const float*)d_in[2];
  const float* MV_ = (const float*)d_in[3];
  float* out = (float*)d_out;

  // ws layout (bytes): khi 33.55M | mkhi 16.78M | partials 3.44M
  const size_t NEED = 53772288;
  if (ws_size >= NEED){
    uint8_t* w8 = (uint8_t*)d_ws;
    ushort* khi  = (ushort*)(w8);
    ushort* mkhi = (ushort*)(w8 + 33554432);
    float*  part = (float*)(w8 + 50331648);
    hipLaunchKernelGGL(kast_cvt3, dim3(12288), dim3(256), 0, stream, K_, MK_,
                       (uint4*)khi, (uint4*)mkhi);
    hipLaunchKernelGGL(kast_attn11, dim3(672), dim3(512), 0, stream, khi, mkhi, V_, MV_, part);
    hipLaunchKernelGGL(kast_merge, dim3(224),  dim3(256), 0, stream, part, out);
  } else {
    hipLaunchKernelGGL(kast_attn_fb, dim3(448), dim3(256), 0, stream, K_, V_, MK_, MV_, out);
  }
  hipLaunchKernelGGL(kast_gt, dim3(56), dim3(256), 0, stream, V_, out);
}

// Round 12
// 133.044 us; speedup vs baseline: 1.6156x; 1.0628x over previous
//
#include <hip/hip_runtime.h>
#include <stdint.h>

typedef _Float16 f16x8 __attribute__((ext_vector_type(8)));
typedef __bf16 bf16x8 __attribute__((ext_vector_type(8)));
typedef float f32x4 __attribute__((ext_vector_type(4)));

#define MFMA_F16(a,b,c) __builtin_amdgcn_mfma_f32_16x16x32_f16(a,b,c,0,0,0)
#define MFMA_BF16(a,b,c) __builtin_amdgcn_mfma_f32_16x16x32_bf16(a,b,c,0,0,0)
#define ALPHA 1.2011224087864498f   // sqrt(log2(e)); both operands scaled -> S in log2 domain

// ---------------- helpers ----------------
__device__ __forceinline__ uint32_t f2u(float x){ union{float f;uint32_t u;} c; c.f=x; return c.u; }
__device__ __forceinline__ float u2f(uint32_t u){ union{float f;uint32_t u;} c; c.u=u; return c.f; }

union HU8 { uint32_t u[4]; _Float16 h[8]; f16x8 v; };

// bf16 truncation split (fallback kernel)
__device__ __forceinline__ void split_pair(float x0, float x1, uint32_t& hp, uint32_t& lp){
  uint32_t u0=f2u(x0), u1=f2u(x1);
  uint32_t h0=u0&0xFFFF0000u, h1=u1&0xFFFF0000u;
  hp = (u0>>16) | h1;
  float l0 = x0 - u2f(h0), l1 = x1 - u2f(h1);
  lp = (f2u(l0)>>16) | (f2u(l1)&0xFFFF0000u);
}

// async global->LDS, 16 bytes per lane. LDS dest = wave-uniform base + lane*16.
__device__ __forceinline__ void glds16(const void* g, void* l){
  __builtin_amdgcn_global_load_lds(
      (const __attribute__((address_space(1))) uint32_t*)(uintptr_t)g,
      (__attribute__((address_space(3))) uint32_t*)(uint32_t)(uintptr_t)l,
      16, 0, 0);
}

// =====================================================================
// Pre-pass (fused K + m_k): ALPHA*x -> f16 RN plane
// =====================================================================
__global__ void kast_cvt3(const float* __restrict__ K_, const float* __restrict__ MK_,
                          uint4* __restrict__ khi, uint4* __restrict__ mkhi){
  int i = blockIdx.x*256 + threadIdx.x;     // 0..3145727
  const float* src; uint4* hi; int j;
  if (i < 2097152){ src = K_;  hi = khi;  j = i; }
  else            { src = MK_; hi = mkhi; j = i - 2097152; }
  const float4* in4 = (const float4*)src;
  float4 a = in4[(size_t)j*2], c = in4[(size_t)j*2+1];
  HU8 h;
  h.h[0]=(_Float16)(a.x*ALPHA); h.h[1]=(_Float16)(a.y*ALPHA);
  h.h[2]=(_Float16)(a.z*ALPHA); h.h[3]=(_Float16)(a.w*ALPHA);
  h.h[4]=(_Float16)(c.x*ALPHA); h.h[5]=(_Float16)(c.y*ALPHA);
  h.h[6]=(_Float16)(c.z*ALPHA); h.h[7]=(_Float16)(c.w*ALPHA);
  hi[j] = make_uint4(h.u[0],h.u[1],h.u[2],h.u[3]);
}

// =====================================================================
// v12 attn: v9 structure + 3-buffer rotation (ONE barrier/tile, DMA gets
// a 2-tile landing window) + defer-max softmax. 1344 blocks x 256 thr.
// Safety: per-wave vmcnt BEFORE the barrier => all waves' DMA for the
// compute buffer landed; write target at iter nt was last read at iter
// nt-1, separated by the barrier at top of nt.
// =====================================================================
__launch_bounds__(256, 2)
__global__ void kast_attn12(const ushort* __restrict__ khi, const ushort* __restrict__ mkhi,
                            const float* __restrict__ V_, const float* __restrict__ MV_,
                            float* __restrict__ part) {
  __shared__ uint8_t KB[3][16384];    // [buf][32 keys x 256 f16], XOR-swizzled granules
  __shared__ float vlds[1536];        // 512 keys x 3 f32

  // XCD-aware decode: slice s on XCD s%8; its 24 blocks share that L2
  const int bid = blockIdx.x;          // 0..1343
  const int xcd = bid & 7;
  const int idx = bid >> 3;            // 0..167
  const int grp = idx / 24;            // 0..6
  const int sub = idx - grp*24;        // 0..23
  const int s   = xcd + 8*grp;         // slice 0..55
  const int qb  = sub & 7;             // q-block 0..7
  const int ks  = sub >> 3;            // key-split 0..2
  const int b = s / 7, t = s % 7;

  const uint8_t* kh8; const float* vbase;
  if (ks < 2){
    size_t row0 = (size_t)((b*8 + t)*1024 + ks*512);
    kh8 = (const uint8_t*)khi + row0*512;
    vbase = V_ + row0*3;
  } else {
    size_t row0 = (size_t)((b*8 + t)*512);
    kh8 = (const uint8_t*)mkhi + row0*512;
    vbase = MV_ + row0*3;
  }

  const int tid = threadIdx.x;
  const int w = tid >> 6, l = tid & 63;
  const int lj = l & 15, lq = l >> 4;
  const int qrow0 = qb*128 + w*32;

  // ---- stage all V (512 x 3 f32) once ----
  for (int i = tid; i < 1536; i += 256) vlds[i] = vbase[i];

  // ---- Q fragments: b128 loads from pre-converted plane ----
  const uint8_t* q8 = (const uint8_t*)khi + (size_t)((b*8 + t + 1)*1024)*512;
  f16x8 qh[2][8];
#pragma unroll
  for (int rt=0; rt<2; rt++){
    const uint8_t* qr = q8 + (size_t)(qrow0 + rt*16 + lj)*512 + lq*16;
#pragma unroll
    for (int kc=0; kc<8; kc++)
      qh[rt][kc] = *(const f16x8*)(qr + kc*64);
  }

  // per-lane online-softmax state (log2 domain, deferred max)
  float m[2][4], ssum[2][4], o[2][4][3];
#pragma unroll
  for (int rt=0;rt<2;rt++)
#pragma unroll
    for (int r=0;r<4;r++){
      m[rt][r]=-1e30f; ssum[rt][r]=0.f;
      o[rt][r][0]=0.f; o[rt][r][1]=0.f; o[rt][r][2]=0.f;
    }

  // DMA: wave stages 8 rows/tile = 4 glds16. per-lane source row = w*8+i*2+(l>>5),
  // granule sg = l&31, pre-swizzled g^(row&7) -> LDS XOR-swizzled, dest linear.
  const int sg = l & 31;
  const int rsub = l >> 5;

  #define ISSUE_TILE(NT, P) do{                                              \
    _Pragma("unroll")                                                        \
    for (int i_=0;i_<4;i_++){                                                \
      int lrow_ = (w<<3) + (i_<<1) + rsub;                                   \
      size_t soff_ = (size_t)((NT)*32 + lrow_)*512 + (size_t)((sg ^ (lrow_&7))<<4); \
      uint32_t dbase_ = ((w<<3) + (i_<<1))*512;                              \
      glds16(kh8 + soff_, &KB[(P)][dbase_]);                                 \
    } }while(0)

  // prologue: tiles 0,1 -> bufs 0,1; syncthreads drains vmcnt + covers V ds_writes
  ISSUE_TILE(0, 0);
  ISSUE_TILE(1, 1);
  __syncthreads();

  int cur = 0, nxt = 2;
  for (int nt=0; nt<16; nt++){
    if (nt < 15){
      asm volatile("s_waitcnt vmcnt(4)" ::: "memory");  // T_nt landed (all older than the 4 newest)
    } else {
      asm volatile("s_waitcnt vmcnt(0)" ::: "memory");  // last tile: drain
    }
    asm volatile("s_barrier" ::: "memory");             // all waves' T_nt landed; prev readers done

    if (nt < 14) ISSUE_TILE(nt+2, nxt);                 // 2-tile landing window

    // ---- MFMA: S = Qh*Kh (log2 domain) ----
    f32x4 acc[2][2];
#pragma unroll
    for (int rt=0;rt<2;rt++){ acc[rt][0]=(f32x4){0,0,0,0}; acc[rt][1]=(f32x4){0,0,0,0}; }

    const int sx = (l&7)<<4;
#pragma unroll
    for (int ct=0;ct<2;ct++){
      const uint8_t* rb = &KB[cur][(ct*16 + lj)*512];
#pragma unroll
      for (int kc=0;kc<8;kc++){
        int bo = (kc*64 + (lq<<4)) ^ sx;
        f16x8 bh = *(const f16x8*)(rb + bo);
        acc[0][ct] = MFMA_F16(qh[0][kc], bh, acc[0][ct]);
        acc[1][ct] = MFMA_F16(qh[1][kc], bh, acc[1][ct]);
      }
    }

    // ---- softmax, exp2 domain with deferred max (THR=24) + PV ----
    float vv[2][3];
#pragma unroll
    for (int ct=0;ct<2;ct++){
      int c = (nt*32 + ct*16 + lj)*3;
      vv[ct][0]=vlds[c]; vv[ct][1]=vlds[c+1]; vv[ct][2]=vlds[c+2];
    }
    float pm[2][4];
    float need = -1e30f;
#pragma unroll
    for (int rt=0;rt<2;rt++)
#pragma unroll
      for (int r=0;r<4;r++){
        pm[rt][r] = fmaxf(acc[rt][0][r], acc[rt][1][r]);
        need = fmaxf(need, pm[rt][r] - m[rt][r]);
      }
    if (need > 24.f){      // rare after tile 0: rescale to new reference
#pragma unroll
      for (int rt=0;rt<2;rt++)
#pragma unroll
        for (int r=0;r<4;r++){
          float mn = fmaxf(m[rt][r], pm[rt][r]);
          float sc = exp2f(m[rt][r] - mn);
          ssum[rt][r] *= sc;
          o[rt][r][0] *= sc; o[rt][r][1] *= sc; o[rt][r][2] *= sc;
          m[rt][r] = mn;
        }
    }
#pragma unroll
    for (int rt=0;rt<2;rt++)
#pragma unroll
      for (int r=0;r<4;r++){
        float p0 = exp2f(acc[rt][0][r] - m[rt][r]);
        float p1 = exp2f(acc[rt][1][r] - m[rt][r]);
        ssum[rt][r] += p0 + p1;
        o[rt][r][0] += p0*vv[0][0] + p1*vv[1][0];
        o[rt][r][1] += p0*vv[0][1] + p1*vv[1][1];
        o[rt][r][2] += p0*vv[0][2] + p1*vv[1][2];
      }

    cur = (cur==2)?0:cur+1;
    nxt = (nxt==2)?0:nxt+1;
  } // nt

  // ---- merge 16 lanes (lj) per row, write partial (m,s,o) ----
#pragma unroll
  for (int rt=0;rt<2;rt++)
#pragma unroll
    for (int r=0;r<4;r++){
      float mm = m[rt][r];
      mm = fmaxf(mm, __shfl_xor(mm,1));
      mm = fmaxf(mm, __shfl_xor(mm,2));
      mm = fmaxf(mm, __shfl_xor(mm,4));
      mm = fmaxf(mm, __shfl_xor(mm,8));
      float f = exp2f(m[rt][r]-mm);
      float sl = ssum[rt][r]*f;
      float o0=o[rt][r][0]*f, o1=o[rt][r][1]*f, o2=o[rt][r][2]*f;
      sl += __shfl_xor(sl,1); sl += __shfl_xor(sl,2); sl += __shfl_xor(sl,4); sl += __shfl_xor(sl,8);
      o0 += __shfl_xor(o0,1); o0 += __shfl_xor(o0,2); o0 += __shfl_xor(o0,4); o0 += __shfl_xor(o0,8);
      o1 += __shfl_xor(o1,1); o1 += __shfl_xor(o1,2); o1 += __shfl_xor(o1,4); o1 += __shfl_xor(o1,8);
      o2 += __shfl_xor(o2,1); o2 += __shfl_xor(o2,2); o2 += __shfl_xor(o2,4); o2 += __shfl_xor(o2,8);
      if (lj == 0){
        int prow = qrow0 + rt*16 + lq*4 + r;
        float* pp = part + ((size_t)(s*3 + ks)*1024 + prow)*5;
        pp[0]=mm; pp[1]=sl; pp[2]=o0; pp[3]=o1; pp[4]=o2;
      }
    }
  #undef ISSUE_TILE
}

// merge 3 partials per q-row -> blended output (m,s are log2-domain)
__global__ void kast_merge(const float* __restrict__ part, float* __restrict__ OUT_){
  int r = blockIdx.x*256 + threadIdx.x;   // 0..57343
  if (r >= 56*1024) return;
  int s = r >> 10, row = r & 1023;
  const float* pa = part + ((size_t)(s*3+0)*1024 + row)*5;
  const float* pb = part + ((size_t)(s*3+1)*1024 + row)*5;
  const float* pm = part + ((size_t)(s*3+2)*1024 + row)*5;
  float ma=pa[0], sa=pa[1], mb=pb[0], sb=pb[1];
  float M = fmaxf(ma,mb);
  float ea = exp2f(ma-M), eb = exp2f(mb-M);
  float w1 = 0.8f / (sa*ea + sb*eb);
  float w2 = 0.2f / pm[1];
  float* op = OUT_ + (size_t)(s*1024 + row)*3;
  op[0] = (pa[2]*ea + pb[2]*eb)*w1 + pm[2]*w2;
  op[1] = (pa[3]*ea + pb[3]*eb)*w1 + pm[3]*w2;
  op[2] = (pa[4]*ea + pb[4]*eb)*w1 + pm[4]*w2;
}

// =====================================================================
// Fallback (round-2 passing kernel) if ws too small
// =====================================================================
__launch_bounds__(256, 2)
__global__ void kast_attn_fb(const float* __restrict__ K_, const float* __restrict__ V_,
                             const float* __restrict__ MK_, const float* __restrict__ MV_,
                             float* __restrict__ OUT_) {
  __shared__ char KhB[64*512];
  __shared__ char KlB[64*512];
  __shared__ float vlds[192];

  const int bid = blockIdx.x;
  const int s  = ((bid>>6)<<3) | (bid & 7);
  const int qb = (bid>>3) & 7;
  const int b = s / 7, t = s % 7;
  const float* qptr = K_ + (size_t)((b*8 + t + 1) * 1024) * 256;
  const float* k1   = K_ + (size_t)((b*8 + t) * 1024) * 256;
  const float* v1   = V_ + (size_t)((b*8 + t) * 1024) * 3;
  const float* k2   = MK_ + (size_t)((b*8 + t) * 512) * 256;
  const float* v2   = MV_ + (size_t)((b*8 + t) * 512) * 3;
  float* outp = OUT_ + (size_t)((b*7 + t) * 1024) * 3;

  const int tid = threadIdx.x;
  const int w = tid >> 6, l = tid & 63;
  const int lj = l & 15, lq = l >> 4;
  const int qrow0 = qb*128 + w*32;

  bf16x8 qh[2][8], ql[2][8];
#pragma unroll
  for (int rt=0; rt<2; rt++){
    const float* qr = qptr + (size_t)(qrow0 + rt*16 + lj)*256 + lq*8;
#pragma unroll
    for (int kc=0; kc<8; kc++){
      float4 a = *(const float4*)(qr + kc*32);
      float4 c = *(const float4*)(qr + kc*32 + 4);
      union { uint32_t d[4]; bf16x8 v; } hh, ll;
      split_pair(a.x, a.y, hh.d[0], ll.d[0]);
      split_pair(a.z, a.w, hh.d[1], ll.d[1]);
      split_pair(c.x, c.y, hh.d[2], ll.d[2]);
      split_pair(c.z, c.w, hh.d[3], ll.d[3]);
      qh[rt][kc]=hh.v; ql[rt][kc]=ll.v;
    }
  }

  for (int ph=0; ph<2; ph++){
    const float* ks = ph ? k2 : k1;
    const float* vs = ph ? v2 : v1;
    const int ntiles = ph ? 8 : 16;
    float m[2][4], ssum[2][4], o[2][4][3];
#pragma unroll
    for (int rt=0;rt<2;rt++)
#pragma unroll
      for (int r=0;r<4;r++){
        m[rt][r]=-1e30f; ssum[rt][r]=0.f;
        o[rt][r][0]=0.f; o[rt][r][1]=0.f; o[rt][r][2]=0.f;
      }

    for (int nt=0; nt<ntiles; nt++){
      __syncthreads();
      const float* kt = ks + (size_t)nt*64*256;
#pragma unroll 4
      for (int i=0;i<16;i++){
        int f4i = tid + i*256;
        int row = f4i >> 6;
        int col4 = f4i & 63;
        float4 x = *(const float4*)(kt + row*256 + col4*4);
        uint32_t hp0,lp0,hp1,lp1;
        split_pair(x.x,x.y,hp0,lp0);
        split_pair(x.z,x.w,hp1,lp1);
        int boff = row*512 + ((col4*8) ^ ((row&7)<<4));
        *(uint2*)(KhB + boff) = make_uint2(hp0,hp1);
        *(uint2*)(KlB + boff) = make_uint2(lp0,lp1);
      }
      if (tid < 192) vlds[tid] = vs[nt*192 + tid];
      __syncthreads();

      f32x4 acc[2][4];
#pragma unroll
      for (int rt=0;rt<2;rt++)
#pragma unroll
        for (int ct=0;ct<4;ct++)
          acc[rt][ct] = (f32x4){0.f,0.f,0.f,0.f};

      const int sx = (l&7)<<4;
#pragma unroll
      for (int ct=0;ct<4;ct++){
        const char* rbh = KhB + (ct*16 + lj)*512;
        const char* rbl = KlB + (ct*16 + lj)*512;
#pragma unroll
        for (int kc=0;kc<8;kc++){
          int bo = (kc*64 + (lq<<4)) ^ sx;
          bf16x8 bh = *(const bf16x8*)(rbh + bo);
          bf16x8 bl = *(const bf16x8*)(rbl + bo);
          acc[0][ct] = MFMA_BF16(qh[0][kc], bh, acc[0][ct]);
          acc[1][ct] = MFMA_BF16(qh[1][kc], bh, acc[1][ct]);
          acc[0][ct] = MFMA_BF16(qh[0][kc], bl, acc[0][ct]);
          acc[1][ct] = MFMA_BF16(qh[1][kc], bl, acc[1][ct]);
          acc[0][ct] = MFMA_BF16(ql[0][kc], bh, acc[0][ct]);
          acc[1][ct] = MFMA_BF16(ql[1][kc], bh, acc[1][ct]);
        }
      }

      float vv[4][3];
#pragma unroll
      for (int ct=0;ct<4;ct++){
        int c = (ct*16 + lj)*3;
        vv[ct][0]=vlds[c]; vv[ct][1]=vlds[c+1]; vv[ct][2]=vlds[c+2];
      }
#pragma unroll
      for (int rt=0;rt<2;rt++)
#pragma unroll
        for (int r=0;r<4;r++){
          float s0=acc[rt][0][r], s1=acc[rt][1][r], s2=acc[rt][2][r], s3=acc[rt][3][r];
          float tmax = fmaxf(fmaxf(s0,s1),fmaxf(s2,s3));
          float mo = m[rt][r];
          float mn = fmaxf(mo, tmax);
          float sc = __expf(mo - mn);
          float p0=__expf(s0-mn), p1=__expf(s1-mn), p2=__expf(s2-mn), p3=__expf(s3-mn);
          ssum[rt][r] = ssum[rt][r]*sc + ((p0+p1)+(p2+p3));
          o[rt][r][0] = o[rt][r][0]*sc + (p0*vv[0][0]+p1*vv[1][0]) + (p2*vv[2][0]+p3*vv[3][0]);
          o[rt][r][1] = o[rt][r][1]*sc + (p0*vv[0][1]+p1*vv[1][1]) + (p2*vv[2][1]+p3*vv[3][1]);
          o[rt][r][2] = o[rt][r][2]*sc + (p0*vv[0][2]+p1*vv[1][2]) + (p2*vv[2][2]+p3*vv[3][2]);
          m[rt][r]=mn;
        }
    }

    const float coef = ph ? 0.2f : 0.8f;
#pragma unroll
    for (int rt=0;rt<2;rt++)
#pragma unroll
      for (int r=0;r<4;r++){
        float mm = m[rt][r];
        mm = fmaxf(mm, __shfl_xor(mm,1));
        mm = fmaxf(mm, __shfl_xor(mm,2));
        mm = fmaxf(mm, __shfl_xor(mm,4));
        mm = fmaxf(mm, __shfl_xor(mm,8));
        float f = __expf(m[rt][r]-mm);
        float sl = ssum[rt][r]*f;
        float o0=o[rt][r][0]*f, o1=o[rt][r][1]*f, o2=o[rt][r][2]*f;
        sl += __shfl_xor(sl,1); sl += __shfl_xor(sl,2); sl += __shfl_xor(sl,4); sl += __shfl_xor(sl,8);
        o0 += __shfl_xor(o0,1); o0 += __shfl_xor(o0,2); o0 += __shfl_xor(o0,4); o0 += __shfl_xor(o0,8);
        o1 += __shfl_xor(o1,1); o1 += __shfl_xor(o1,2); o1 += __shfl_xor(o1,4); o1 += __shfl_xor(o1,8);
        o2 += __shfl_xor(o2,1); o2 += __shfl_xor(o2,2); o2 += __shfl_xor(o2,4); o2 += __shfl_xor(o2,8);
        if (lj == 0){
          int row = qrow0 + rt*16 + lq*4 + r;
          float* op = outp + (size_t)row*3;
          float invs = coef / sl;
          if (ph==0){ op[0]=o0*invs; op[1]=o1*invs; op[2]=o2*invs; }
          else      { op[0]+=o0*invs; op[1]+=o1*invs; op[2]+=o2*invs; }
        }
      }
  }
}

// ground truth = v[:,1:] (second output, exact copy)
__global__ void kast_gt(const float* __restrict__ V_, float* __restrict__ OUT_){
  int s = blockIdx.x; int b = s/7, t = s%7;
  const float4* src = (const float4*)(V_ + (size_t)(b*8+t+1)*3072);
  float4* dst = (float4*)(OUT_ + 172032 + (size_t)s*3072);
  for (int i=threadIdx.x; i<768; i+=256) dst[i] = src[i];
}

extern "C" void kernel_launch(void* const* d_in, const int* in_sizes, int n_in,
                              void* d_out, int out_size, void* d_ws, size_t ws_size,
                              hipStream_t stream) {
  (void)in_sizes; (void)n_in; (void)out_size;
  const float* K_  = (const float*)d_in[0];
  const float* V_  = (const float*)d_in[1];
  const float* MK_ = (const float*)d_in[2];
  const float* MV_ = (const float*)d_in[3];
  float* out = (float*)d_out;

  // ws layout (bytes): khi 33.55M | mkhi 16.78M | partials 3.44M
  const size_t NEED = 53772288;
  if (ws_size >= NEED){
    uint8_t* w8 = (uint8_t*)d_ws;
    ushort* khi  = (ushort*)(w8);
    ushort* mkhi = (ushort*)(w8 + 33554432);
    float*  part = (float*)(w8 + 50331648);
    hipLaunchKernelGGL(kast_cvt3, dim3(12288), dim3(256), 0, stream, K_, MK_,
                       (uint4*)khi, (uint4*)mkhi);
    hipLaunchKernelGGL(kast_attn12, dim3(1344), dim3(256), 0, stream, khi, mkhi, V_, MV_, part);
    hipLaunchKernelGGL(kast_merge, dim3(224),  dim3(256), 0, stream, part, out);
  } else {
    hipLaunchKernelGGL(kast_attn_fb, dim3(448), dim3(256), 0, stream, K_, V_, MK_, MV_, out);
  }
  hipLaunchKernelGGL(kast_gt, dim3(56), dim3(256), 0, stream, V_, out);
}

// Round 15
// 113.622 us; speedup vs baseline: 1.8918x; 1.1709x over previous
//
#include <hip/hip_runtime.h>
#include <stdint.h>

typedef _Float16 f16x8 __attribute__((ext_vector_type(8)));
typedef __bf16 bf16x8 __attribute__((ext_vector_type(8)));
typedef float f32x4 __attribute__((ext_vector_type(4)));

#define MFMA_F16(a,b,c) __builtin_amdgcn_mfma_f32_16x16x32_f16(a,b,c,0,0,0)
#define MFMA_BF16(a,b,c) __builtin_amdgcn_mfma_f32_16x16x32_bf16(a,b,c,0,0,0)
#define ALPHA 1.2011224087864498f   // sqrt(log2(e)); both operands scaled -> S in log2 domain
#define EXP2R(x) __builtin_amdgcn_exp2f(x)   // raw v_exp_f32 (args bounded by defer-max)

// ---------------- helpers ----------------
__device__ __forceinline__ uint32_t f2u(float x){ union{float f;uint32_t u;} c; c.f=x; return c.u; }
__device__ __forceinline__ float u2f(uint32_t u){ union{float f;uint32_t u;} c; c.u=u; return c.f; }

union HU8 { uint32_t u[4]; _Float16 h[8]; f16x8 v; };

// bf16 truncation split (fallback kernel)
__device__ __forceinline__ void split_pair(float x0, float x1, uint32_t& hp, uint32_t& lp){
  uint32_t u0=f2u(x0), u1=f2u(x1);
  uint32_t h0=u0&0xFFFF0000u, h1=u1&0xFFFF0000u;
  hp = (u0>>16) | h1;
  float l0 = x0 - u2f(h0), l1 = x1 - u2f(h1);
  lp = (f2u(l0)>>16) | (f2u(l1)&0xFFFF0000u);
}

// async global->LDS, 16 bytes per lane. LDS dest = wave-uniform base + lane*16.
__device__ __forceinline__ void glds16(const void* g, void* l){
  __builtin_amdgcn_global_load_lds(
      (const __attribute__((address_space(1))) uint32_t*)(uintptr_t)g,
      (__attribute__((address_space(3))) uint32_t*)(uint32_t)(uintptr_t)l,
      16, 0, 0);
}

// =====================================================================
// Pre-pass (fused K + m_k): ALPHA*x -> f16 RN plane
// =====================================================================
__global__ void kast_cvt3(const float* __restrict__ K_, const float* __restrict__ MK_,
                          uint4* __restrict__ khi, uint4* __restrict__ mkhi){
  int i = blockIdx.x*256 + threadIdx.x;     // 0..3145727
  const float* src; uint4* hi; int j;
  if (i < 2097152){ src = K_;  hi = khi;  j = i; }
  else            { src = MK_; hi = mkhi; j = i - 2097152; }
  const float4* in4 = (const float4*)src;
  float4 a = in4[(size_t)j*2], c = in4[(size_t)j*2+1];
  HU8 h;
  h.h[0]=(_Float16)(a.x*ALPHA); h.h[1]=(_Float16)(a.y*ALPHA);
  h.h[2]=(_Float16)(a.z*ALPHA); h.h[3]=(_Float16)(a.w*ALPHA);
  h.h[4]=(_Float16)(c.x*ALPHA); h.h[5]=(_Float16)(c.y*ALPHA);
  h.h[6]=(_Float16)(c.z*ALPHA); h.h[7]=(_Float16)(c.w*ALPHA);
  hi[j] = make_uint4(h.u[0],h.u[1],h.u[2],h.u[3]);
}

// =====================================================================
// v14 attn: v9 skeleton (2-buffer dbuf, vmcnt(4), 2 barriers/tile, 35KB
// LDS -> 4 blocks/CU) + 6-way key split (grid 2688, 8 tiles/block) +
// raw v_exp_f32 + defer-max softmax.
// =====================================================================
__launch_bounds__(256, 2)
__global__ void kast_attn14(const ushort* __restrict__ khi, const ushort* __restrict__ mkhi,
                            const float* __restrict__ V_, const float* __restrict__ MV_,
                            float* __restrict__ part) {
  __shared__ uint8_t KB[2][16384];    // [buf][32 keys x 256 f16], XOR-swizzled granules
  __shared__ float vlds[768];         // 256 keys x 3 f32

  // XCD-aware decode: slice s on XCD s%8; its 48 blocks share that L2
  const int bid = blockIdx.x;          // 0..2687
  const int xcd = bid & 7;
  const int idx = bid >> 3;            // 0..335
  const int grp = idx / 48;            // 0..6
  const int sub = idx - grp*48;        // 0..47
  const int s   = xcd + 8*grp;         // slice 0..55
  const int qb  = sub & 7;             // q-block 0..7
  const int ks  = sub >> 3;            // key-split 0..5
  const int b = s / 7, t = s % 7;

  const uint8_t* kh8; const float* vbase;
  if (ks < 4){
    size_t row0 = (size_t)((b*8 + t)*1024 + ks*256);
    kh8 = (const uint8_t*)khi + row0*512;
    vbase = V_ + row0*3;
  } else {
    size_t row0 = (size_t)((b*8 + t)*512 + (ks-4)*256);
    kh8 = (const uint8_t*)mkhi + row0*512;
    vbase = MV_ + row0*3;
  }

  const int tid = threadIdx.x;
  const int w = tid >> 6, l = tid & 63;
  const int lj = l & 15, lq = l >> 4;
  const int qrow0 = qb*128 + w*32;

  // ---- stage V (256 x 3 f32) once ----
  for (int i = tid; i < 768; i += 256) vlds[i] = vbase[i];

  // ---- Q fragments: b128 loads from pre-converted plane ----
  const uint8_t* q8 = (const uint8_t*)khi + (size_t)((b*8 + t + 1)*1024)*512;
  f16x8 qh[2][8];
#pragma unroll
  for (int rt=0; rt<2; rt++){
    const uint8_t* qr = q8 + (size_t)(qrow0 + rt*16 + lj)*512 + lq*16;
#pragma unroll
    for (int kc=0; kc<8; kc++)
      qh[rt][kc] = *(const f16x8*)(qr + kc*64);
  }

  // per-lane online-softmax state (log2 domain, deferred max)
  float m[2][4], ssum[2][4], o[2][4][3];
#pragma unroll
  for (int rt=0;rt<2;rt++)
#pragma unroll
    for (int r=0;r<4;r++){
      m[rt][r]=-1e30f; ssum[rt][r]=0.f;
      o[rt][r][0]=0.f; o[rt][r][1]=0.f; o[rt][r][2]=0.f;
    }

  // DMA: wave stages 8 rows/tile = 4 glds16. per-lane source row = w*8+i*2+(l>>5),
  // granule sg = l&31, pre-swizzled g^(row&7) -> LDS XOR-swizzled, dest linear.
  const int sg = l & 31;
  const int rsub = l >> 5;

  #define ISSUE_TILE(NT, P) do{                                              \
    _Pragma("unroll")                                                        \
    for (int i_=0;i_<4;i_++){                                                \
      int lrow_ = (w<<3) + (i_<<1) + rsub;                                   \
      size_t soff_ = (size_t)((NT)*32 + lrow_)*512 + (size_t)((sg ^ (lrow_&7))<<4); \
      uint32_t dbase_ = ((w<<3) + (i_<<1))*512;                              \
      glds16(kh8 + soff_, &KB[(P)][dbase_]);                                 \
    } }while(0)

  // prologue: tile 0 -> buf 0; full sync also covers V-staging ds_writes
  ISSUE_TILE(0, 0);
  __syncthreads();

  for (int nt=0; nt<8; nt++){
    const int cur = nt & 1;
    if (nt < 7){
      ISSUE_TILE(nt+1, cur^1);
      asm volatile("s_waitcnt vmcnt(4)" ::: "memory");  // cur tile's 4 DMA done; next 4 in flight
    } else {
      asm volatile("s_waitcnt vmcnt(0)" ::: "memory");
    }
    asm volatile("s_barrier" ::: "memory");             // all waves: buf[cur] ready

    // ---- MFMA: S = Qh*Kh (log2 domain) ----
    f32x4 acc[2][2];
#pragma unroll
    for (int rt=0;rt<2;rt++){ acc[rt][0]=(f32x4){0,0,0,0}; acc[rt][1]=(f32x4){0,0,0,0}; }

    const int sx = (l&7)<<4;
#pragma unroll
    for (int ct=0;ct<2;ct++){
      const uint8_t* rb = &KB[cur][(ct*16 + lj)*512];
#pragma unroll
      for (int kc=0;kc<8;kc++){
        int bo = (kc*64 + (lq<<4)) ^ sx;
        f16x8 bh = *(const f16x8*)(rb + bo);
        acc[0][ct] = MFMA_F16(qh[0][kc], bh, acc[0][ct]);
        acc[1][ct] = MFMA_F16(qh[1][kc], bh, acc[1][ct]);
      }
    }

    // ---- softmax, exp2 domain with deferred max (THR=24) + PV ----
    float vv[2][3];
#pragma unroll
    for (int ct=0;ct<2;ct++){
      int c = (nt*32 + ct*16 + lj)*3;
      vv[ct][0]=vlds[c]; vv[ct][1]=vlds[c+1]; vv[ct][2]=vlds[c+2];
    }
    float pm[2][4];
    float need = -1e30f;
#pragma unroll
    for (int rt=0;rt<2;rt++)
#pragma unroll
      for (int r=0;r<4;r++){
        pm[rt][r] = fmaxf(acc[rt][0][r], acc[rt][1][r]);
        need = fmaxf(need, pm[rt][r] - m[rt][r]);
      }
    if (need > 24.f){      // fires at tile 0 and rarely after: rescale
#pragma unroll
      for (int rt=0;rt<2;rt++)
#pragma unroll
        for (int r=0;r<4;r++){
          float mn = fmaxf(m[rt][r], pm[rt][r]);
          float sc = EXP2R(m[rt][r] - mn);
          ssum[rt][r] *= sc;
          o[rt][r][0] *= sc; o[rt][r][1] *= sc; o[rt][r][2] *= sc;
          m[rt][r] = mn;
        }
    }
#pragma unroll
    for (int rt=0;rt<2;rt++)
#pragma unroll
      for (int r=0;r<4;r++){
        float p0 = EXP2R(acc[rt][0][r] - m[rt][r]);
        float p1 = EXP2R(acc[rt][1][r] - m[rt][r]);
        ssum[rt][r] += p0 + p1;
        o[rt][r][0] += p0*vv[0][0] + p1*vv[1][0];
        o[rt][r][1] += p0*vv[0][1] + p1*vv[1][1];
        o[rt][r][2] += p0*vv[0][2] + p1*vv[1][2];
      }

    asm volatile("s_barrier" ::: "memory");             // all waves done reading buf[cur]
  } // nt

  // ---- merge 16 lanes (lj) per row, write partial (m,s,o) ----
#pragma unroll
  for (int rt=0;rt<2;rt++)
#pragma unroll
    for (int r=0;r<4;r++){
      float mm = m[rt][r];
      mm = fmaxf(mm, __shfl_xor(mm,1));
      mm = fmaxf(mm, __shfl_xor(mm,2));
      mm = fmaxf(mm, __shfl_xor(mm,4));
      mm = fmaxf(mm, __shfl_xor(mm,8));
      float f = EXP2R(m[rt][r]-mm);
      float sl = ssum[rt][r]*f;
      float o0=o[rt][r][0]*f, o1=o[rt][r][1]*f, o2=o[rt][r][2]*f;
      sl += __shfl_xor(sl,1); sl += __shfl_xor(sl,2); sl += __shfl_xor(sl,4); sl += __shfl_xor(sl,8);
      o0 += __shfl_xor(o0,1); o0 += __shfl_xor(o0,2); o0 += __shfl_xor(o0,4); o0 += __shfl_xor(o0,8);
      o1 += __shfl_xor(o1,1); o1 += __shfl_xor(o1,2); o1 += __shfl_xor(o1,4); o1 += __shfl_xor(o1,8);
      o2 += __shfl_xor(o2,1); o2 += __shfl_xor(o2,2); o2 += __shfl_xor(o2,4); o2 += __shfl_xor(o2,8);
      if (lj == 0){
        int prow = qrow0 + rt*16 + lq*4 + r;
        float* pp = part + ((size_t)(s*6 + ks)*1024 + prow)*5;
        pp[0]=mm; pp[1]=sl; pp[2]=o0; pp[3]=o1; pp[4]=o2;
      }
    }
  #undef ISSUE_TILE
}

// merge 6 partials per q-row (4 K-parts, 2 M-parts) -> blended output
// FIXED (r14 bug): part stride is (1024*5) floats, not 5.
__global__ void kast_merge6(const float* __restrict__ part, float* __restrict__ OUT_){
  int r = blockIdx.x*256 + threadIdx.x;   // 0..57343
  if (r >= 56*1024) return;
  int s = r >> 10, row = r & 1023;
  const float* p[6];
#pragma unroll
  for (int i=0;i<6;i++) p[i] = part + ((size_t)(s*6+i)*1024 + row)*5;
  // K-attn: parts 0..3
  float M1 = fmaxf(fmaxf(p[0][0], p[1][0]), fmaxf(p[2][0], p[3][0]));
  float sK = 0.f, oK0 = 0.f, oK1 = 0.f, oK2 = 0.f;
#pragma unroll
  for (int i=0;i<4;i++){
    float e = EXP2R(p[i][0]-M1);
    sK += p[i][1]*e; oK0 += p[i][2]*e; oK1 += p[i][3]*e; oK2 += p[i][4]*e;
  }
  // M-attn: parts 4..5
  float M2 = fmaxf(p[4][0], p[5][0]);
  float e0 = EXP2R(p[4][0]-M2), e1 = EXP2R(p[5][0]-M2);
  float sM = p[4][1]*e0 + p[5][1]*e1;
  float w1 = 0.8f / sK;
  float w2 = 0.2f / sM;
  float* op = OUT_ + (size_t)(s*1024 + row)*3;
  op[0] = oK0*w1 + (p[4][2]*e0 + p[5][2]*e1)*w2;
  op[1] = oK1*w1 + (p[4][3]*e0 + p[5][3]*e1)*w2;
  op[2] = oK2*w1 + (p[4][4]*e0 + p[5][4]*e1)*w2;
}

// =====================================================================
// Fallback (round-2 passing kernel) if ws too small
// =====================================================================
__launch_bounds__(256, 2)
__global__ void kast_attn_fb(const float* __restrict__ K_, const float* __restrict__ V_,
                             const float* __restrict__ MK_, const float* __restrict__ MV_,
                             float* __restrict__ OUT_) {
  __shared__ char KhB[64*512];
  __shared__ char KlB[64*512];
  __shared__ float vlds[192];

  const int bid = blockIdx.x;
  const int s  = ((bid>>6)<<3) | (bid & 7);
  const int qb = (bid>>3) & 7;
  const int b = s / 7, t = s % 7;
  const float* qptr = K_ + (size_t)((b*8 + t + 1) * 1024) * 256;
  const float* k1   = K_ + (size_t)((b*8 + t) * 1024) * 256;
  const float* v1   = V_ + (size_t)((b*8 + t) * 1024) * 3;
  const float* k2   = MK_ + (size_t)((b*8 + t) * 512) * 256;
  const float* v2   = MV_ + (size_t)((b*8 + t) * 512) * 3;
  float* outp = OUT_ + (size_t)((b*7 + t) * 1024) * 3;

  const int tid = threadIdx.x;
  const int w = tid >> 6, l = tid & 63;
  const int lj = l & 15, lq = l >> 4;
  const int qrow0 = qb*128 + w*32;

  bf16x8 qh[2][8], ql[2][8];
#pragma unroll
  for (int rt=0; rt<2; rt++){
    const float* qr = qptr + (size_t)(qrow0 + rt*16 + lj)*256 + lq*8;
#pragma unroll
    for (int kc=0; kc<8; kc++){
      float4 a = *(const float4*)(qr + kc*32);
      float4 c = *(const float4*)(qr + kc*32 + 4);
      union { uint32_t d[4]; bf16x8 v; } hh, ll;
      split_pair(a.x, a.y, hh.d[0], ll.d[0]);
      split_pair(a.z, a.w, hh.d[1], ll.d[1]);
      split_pair(c.x, c.y, hh.d[2], ll.d[2]);
      split_pair(c.z, c.w, hh.d[3], ll.d[3]);
      qh[rt][kc]=hh.v; ql[rt][kc]=ll.v;
    }
  }

  for (int ph=0; ph<2; ph++){
    const float* ks = ph ? k2 : k1;
    const float* vs = ph ? v2 : v1;
    const int ntiles = ph ? 8 : 16;
    float m[2][4], ssum[2][4], o[2][4][3];
#pragma unroll
    for (int rt=0;rt<2;rt++)
#pragma unroll
      for (int r=0;r<4;r++){
        m[rt][r]=-1e30f; ssum[rt][r]=0.f;
        o[rt][r][0]=0.f; o[rt][r][1]=0.f; o[rt][r][2]=0.f;
      }

    for (int nt=0; nt<ntiles; nt++){
      __syncthreads();
      const float* kt = ks + (size_t)nt*64*256;
#pragma unroll 4
      for (int i=0;i<16;i++){
        int f4i = tid + i*256;
        int row = f4i >> 6;
        int col4 = f4i & 63;
        float4 x = *(const float4*)(kt + row*256 + col4*4);
        uint32_t hp0,lp0,hp1,lp1;
        split_pair(x.x,x.y,hp0,lp0);
        split_pair(x.z,x.w,hp1,lp1);
        int boff = row*512 + ((col4*8) ^ ((row&7)<<4));
        *(uint2*)(KhB + boff) = make_uint2(hp0,hp1);
        *(uint2*)(KlB + boff) = make_uint2(lp0,lp1);
      }
      if (tid < 192) vlds[tid] = vs[nt*192 + tid];
      __syncthreads();

      f32x4 acc[2][4];
#pragma unroll
      for (int rt=0;rt<2;rt++)
#pragma unroll
        for (int ct=0;ct<4;ct++)
          acc[rt][ct] = (f32x4){0.f,0.f,0.f,0.f};

      const int sx = (l&7)<<4;
#pragma unroll
      for (int ct=0;ct<4;ct++){
        const char* rbh = KhB + (ct*16 + lj)*512;
        const char* rbl = KlB + (ct*16 + lj)*512;
#pragma unroll
        for (int kc=0;kc<8;kc++){
          int bo = (kc*64 + (lq<<4)) ^ sx;
          bf16x8 bh = *(const bf16x8*)(rbh + bo);
          bf16x8 bl = *(const bf16x8*)(rbl + bo);
          acc[0][ct] = MFMA_BF16(qh[0][kc], bh, acc[0][ct]);
          acc[1][ct] = MFMA_BF16(qh[1][kc], bh, acc[1][ct]);
          acc[0][ct] = MFMA_BF16(qh[0][kc], bl, acc[0][ct]);
          acc[1][ct] = MFMA_BF16(qh[1][kc], bl, acc[1][ct]);
          acc[0][ct] = MFMA_BF16(ql[0][kc], bh, acc[0][ct]);
          acc[1][ct] = MFMA_BF16(ql[1][kc], bh, acc[1][ct]);
        }
      }

      float vv[4][3];
#pragma unroll
      for (int ct=0;ct<4;ct++){
        int c = (ct*16 + lj)*3;
        vv[ct][0]=vlds[c]; vv[ct][1]=vlds[c+1]; vv[ct][2]=vlds[c+2];
      }
#pragma unroll
      for (int rt=0;rt<2;rt++)
#pragma unroll
        for (int r=0;r<4;r++){
          float s0=acc[rt][0][r], s1=acc[rt][1][r], s2=acc[rt][2][r], s3=acc[rt][3][r];
          float tmax = fmaxf(fmaxf(s0,s1),fmaxf(s2,s3));
          float mo = m[rt][r];
          float mn = fmaxf(mo, tmax);
          float sc = __expf(mo - mn);
          float p0=__expf(s0-mn), p1=__expf(s1-mn), p2=__expf(s2-mn), p3=__expf(s3-mn);
          ssum[rt][r] = ssum[rt][r]*sc + ((p0+p1)+(p2+p3));
          o[rt][r][0] = o[rt][r][0]*sc + (p0*vv[0][0]+p1*vv[1][0]) + (p2*vv[2][0]+p3*vv[3][0]);
          o[rt][r][1] = o[rt][r][1]*sc + (p0*vv[0][1]+p1*vv[1][1]) + (p2*vv[2][1]+p3*vv[3][1]);
          o[rt][r][2] = o[rt][r][2]*sc + (p0*vv[0][2]+p1*vv[1][2]) + (p2*vv[2][2]+p3*vv[3][2]);
          m[rt][r]=mn;
        }
    }

    const float coef = ph ? 0.2f : 0.8f;
#pragma unroll
    for (int rt=0;rt<2;rt++)
#pragma unroll
      for (int r=0;r<4;r++){
        float mm = m[rt][r];
        mm = fmaxf(mm, __shfl_xor(mm,1));
        mm = fmaxf(mm, __shfl_xor(mm,2));
        mm = fmaxf(mm, __shfl_xor(mm,4));
        mm = fmaxf(mm, __shfl_xor(mm,8));
        float f = __expf(m[rt][r]-mm);
        float sl = ssum[rt][r]*f;
        float o0=o[rt][r][0]*f, o1=o[rt][r][1]*f, o2=o[rt][r][2]*f;
        sl += __shfl_xor(sl,1); sl += __shfl_xor(sl,2); sl += __shfl_xor(sl,4); sl += __shfl_xor(sl,8);
        o0 += __shfl_xor(o0,1); o0 += __shfl_xor(o0,2); o0 += __shfl_xor(o0,4); o0 += __shfl_xor(o0,8);
        o1 += __shfl_xor(o1,1); o1 += __shfl_xor(o1,2); o1 += __shfl_xor(o1,4); o1 += __shfl_xor(o1,8);
        o2 += __shfl_xor(o2,1); o2 += __shfl_xor(o2,2); o2 += __shfl_xor(o2,4); o2 += __shfl_xor(o2,8);
        if (lj == 0){
          int row = qrow0 + rt*16 + lq*4 + r;
          float* op = outp + (size_t)row*3;
          float invs = coef / sl;
          if (ph==0){ op[0]=o0*invs; op[1]=o1*invs; op[2]=o2*invs; }
          else      { op[0]+=o0*invs; op[1]+=o1*invs; op[2]+=o2*invs; }
        }
      }
  }
}

// ground truth = v[:,1:] (second output, exact copy)
__global__ void kast_gt(const float* __restrict__ V_, float* __restrict__ OUT_){
  int s = blockIdx.x; int b = s/7, t = s%7;
  const float4* src = (const float4*)(V_ + (size_t)(b*8+t+1)*3072);
  float4* dst = (float4*)(OUT_ + 172032 + (size_t)s*3072);
  for (int i=threadIdx.x; i<768; i+=256) dst[i] = src[i];
}

extern "C" void kernel_launch(void* const* d_in, const int* in_sizes, int n_in,
                              void* d_out, int out_size, void* d_ws, size_t ws_size,
                              hipStream_t stream) {
  (void)in_sizes; (void)n_in; (void)out_size;
  const float* K_  = (const float*)d_in[0];
  const float* V_  = (const float*)d_in[1];
  const float* MK_ = (const float*)d_in[2];
  const float* MV_ = (const float*)d_in[3];
  float* out = (float*)d_out;

  // ws layout (bytes): khi 33.55M | mkhi 16.78M | partials 6.88M
  const size_t NEED = 57212928;
  if (ws_size >= NEED){
    uint8_t* w8 = (uint8_t*)d_ws;
    ushort* khi  = (ushort*)(w8);
    ushort* mkhi = (ushort*)(w8 + 33554432);
    float*  part = (float*)(w8 + 50331648);
    hipLaunchKernelGGL(kast_cvt3, dim3(12288), dim3(256), 0, stream, K_, MK_,
                       (uint4*)khi, (uint4*)mkhi);
    hipLaunchKernelGGL(kast_attn14, dim3(2688), dim3(256), 0, stream, khi, mkhi, V_, MV_, part);
    hipLaunchKernelGGL(kast_merge6, dim3(224),  dim3(256), 0, stream, part, out);
  } else {
    hipLaunchKernelGGL(kast_attn_fb, dim3(448), dim3(256), 0, stream, K_, V_, MK_, MV_, out);
  }
  hipLaunchKernelGGL(kast_gt, dim3(56), dim3(256), 0, stream, V_, out);
}

// Round 17
// 112.782 us; speedup vs baseline: 1.9059x; 1.0074x over previous
//
#include <hip/hip_runtime.h>
#include <stdint.h>

typedef _Float16 f16x8 __attribute__((ext_vector_type(8)));
typedef __bf16 bf16x8 __attribute__((ext_vector_type(8)));
typedef float f32x4 __attribute__((ext_vector_type(4)));

#define MFMA_F16(a,b,c) __builtin_amdgcn_mfma_f32_16x16x32_f16(a,b,c,0,0,0)
#define MFMA_BF16(a,b,c) __builtin_amdgcn_mfma_f32_16x16x32_bf16(a,b,c,0,0,0)
#define ALPHA 1.2011224087864498f   // sqrt(log2(e)); both operands scaled -> S in log2 domain
#define EXP2R(x) __builtin_amdgcn_exp2f(x)   // raw v_exp_f32 (args bounded by defer-max)

// ---------------- helpers ----------------
__device__ __forceinline__ uint32_t f2u(float x){ union{float f;uint32_t u;} c; c.f=x; return c.u; }
__device__ __forceinline__ float u2f(uint32_t u){ union{float f;uint32_t u;} c; c.u=u; return c.f; }

union HU8 { uint32_t u[4]; _Float16 h[8]; f16x8 v; };

// bf16 truncation split (fallback kernel)
__device__ __forceinline__ void split_pair(float x0, float x1, uint32_t& hp, uint32_t& lp){
  uint32_t u0=f2u(x0), u1=f2u(x1);
  uint32_t h0=u0&0xFFFF0000u, h1=u1&0xFFFF0000u;
  hp = (u0>>16) | h1;
  float l0 = x0 - u2f(h0), l1 = x1 - u2f(h1);
  lp = (f2u(l0)>>16) | (f2u(l1)&0xFFFF0000u);
}

// async global->LDS, 16 bytes per lane. LDS dest = wave-uniform base + lane*16.
__device__ __forceinline__ void glds16(const void* g, void* l){
  __builtin_amdgcn_global_load_lds(
      (const __attribute__((address_space(1))) uint32_t*)(uintptr_t)g,
      (__attribute__((address_space(3))) uint32_t*)(uint32_t)(uintptr_t)l,
      16, 0, 0);
}

// =====================================================================
// Pre-pass (fused K + m_k): ALPHA*x -> f16 RN plane
// =====================================================================
__global__ void kast_cvt3(const float* __restrict__ K_, const float* __restrict__ MK_,
                          uint4* __restrict__ khi, uint4* __restrict__ mkhi){
  int i = blockIdx.x*256 + threadIdx.x;     // 0..3145727
  const float* src; uint4* hi; int j;
  if (i < 2097152){ src = K_;  hi = khi;  j = i; }
  else            { src = MK_; hi = mkhi; j = i - 2097152; }
  const float4* in4 = (const float4*)src;
  float4 a = in4[(size_t)j*2], c = in4[(size_t)j*2+1];
  HU8 h;
  h.h[0]=(_Float16)(a.x*ALPHA); h.h[1]=(_Float16)(a.y*ALPHA);
  h.h[2]=(_Float16)(a.z*ALPHA); h.h[3]=(_Float16)(a.w*ALPHA);
  h.h[4]=(_Float16)(c.x*ALPHA); h.h[5]=(_Float16)(c.y*ALPHA);
  h.h[6]=(_Float16)(c.z*ALPHA); h.h[7]=(_Float16)(c.w*ALPHA);
  hi[j] = make_uint4(h.u[0],h.u[1],h.u[2],h.u[3]);
}

// =====================================================================
// v16 attn: v14 + ONE barrier/tile. Order per tile:
//   vmcnt(0) -> s_barrier -> ISSUE(nt+1 -> buf^1) -> compute(buf)
// Safety: passing barrier(nt) => all waves finished iter nt-1 compute,
// so all reads of buf^1 are done before the DMA issue targets it; each
// wave's vmcnt(0) BEFORE the barrier certifies its tile-nt DMA landed.
// + s_setprio around the MFMA cluster (T5, attn-positive m191).
// =====================================================================
__launch_bounds__(256, 2)
__global__ void kast_attn16(const ushort* __restrict__ khi, const ushort* __restrict__ mkhi,
                            const float* __restrict__ V_, const float* __restrict__ MV_,
                            float* __restrict__ part) {
  __shared__ uint8_t KB[2][16384];    // [buf][32 keys x 256 f16], XOR-swizzled granules
  __shared__ float vlds[768];         // 256 keys x 3 f32

  // XCD-aware decode: slice s on XCD s%8; its 48 blocks share that L2
  const int bid = blockIdx.x;          // 0..2687
  const int xcd = bid & 7;
  const int idx = bid >> 3;            // 0..335
  const int grp = idx / 48;            // 0..6
  const int sub = idx - grp*48;        // 0..47
  const int s   = xcd + 8*grp;         // slice 0..55
  const int qb  = sub & 7;             // q-block 0..7
  const int ks  = sub >> 3;            // key-split 0..5
  const int b = s / 7, t = s % 7;

  const uint8_t* kh8; const float* vbase;
  if (ks < 4){
    size_t row0 = (size_t)((b*8 + t)*1024 + ks*256);
    kh8 = (const uint8_t*)khi + row0*512;
    vbase = V_ + row0*3;
  } else {
    size_t row0 = (size_t)((b*8 + t)*512 + (ks-4)*256);
    kh8 = (const uint8_t*)mkhi + row0*512;
    vbase = MV_ + row0*3;
  }

  const int tid = threadIdx.x;
  const int w = tid >> 6, l = tid & 63;
  const int lj = l & 15, lq = l >> 4;
  const int qrow0 = qb*128 + w*32;

  // ---- stage V (256 x 3 f32) once ----
  for (int i = tid; i < 768; i += 256) vlds[i] = vbase[i];

  // ---- Q fragments: b128 loads from pre-converted plane ----
  const uint8_t* q8 = (const uint8_t*)khi + (size_t)((b*8 + t + 1)*1024)*512;
  f16x8 qh[2][8];
#pragma unroll
  for (int rt=0; rt<2; rt++){
    const uint8_t* qr = q8 + (size_t)(qrow0 + rt*16 + lj)*512 + lq*16;
#pragma unroll
    for (int kc=0; kc<8; kc++)
      qh[rt][kc] = *(const f16x8*)(qr + kc*64);
  }

  // per-lane online-softmax state (log2 domain, deferred max)
  float m[2][4], ssum[2][4], o[2][4][3];
#pragma unroll
  for (int rt=0;rt<2;rt++)
#pragma unroll
    for (int r=0;r<4;r++){
      m[rt][r]=-1e30f; ssum[rt][r]=0.f;
      o[rt][r][0]=0.f; o[rt][r][1]=0.f; o[rt][r][2]=0.f;
    }

  // DMA: wave stages 8 rows/tile = 4 glds16. per-lane source row = w*8+i*2+(l>>5),
  // granule sg = l&31, pre-swizzled g^(row&7) -> LDS XOR-swizzled, dest linear.
  const int sg = l & 31;
  const int rsub = l >> 5;

  #define ISSUE_TILE(NT, P) do{                                              \
    _Pragma("unroll")                                                        \
    for (int i_=0;i_<4;i_++){                                                \
      int lrow_ = (w<<3) + (i_<<1) + rsub;                                   \
      size_t soff_ = (size_t)((NT)*32 + lrow_)*512 + (size_t)((sg ^ (lrow_&7))<<4); \
      uint32_t dbase_ = ((w<<3) + (i_<<1))*512;                              \
      glds16(kh8 + soff_, &KB[(P)][dbase_]);                                 \
    } }while(0)

  // prologue: tile 0 -> buf 0; full sync also covers V-staging ds_writes
  ISSUE_TILE(0, 0);
  __syncthreads();

  for (int nt=0; nt<8; nt++){
    const int cur = nt & 1;
    asm volatile("s_waitcnt vmcnt(0)" ::: "memory");   // my tile-nt DMA landed
    asm volatile("s_barrier" ::: "memory");            // => ALL waves' tile-nt landed;
                                                       //    all reads of buf^1 (iter nt-1) done
    if (nt < 7) ISSUE_TILE(nt+1, cur^1);               // full compute phase to land

    // ---- MFMA: S = Qh*Kh (log2 domain) ----
    f32x4 acc[2][2];
#pragma unroll
    for (int rt=0;rt<2;rt++){ acc[rt][0]=(f32x4){0,0,0,0}; acc[rt][1]=(f32x4){0,0,0,0}; }

    const int sx = (l&7)<<4;
    __builtin_amdgcn_s_setprio(1);
#pragma unroll
    for (int ct=0;ct<2;ct++){
      const uint8_t* rb = &KB[cur][(ct*16 + lj)*512];
#pragma unroll
      for (int kc=0;kc<8;kc++){
        int bo = (kc*64 + (lq<<4)) ^ sx;
        f16x8 bh = *(const f16x8*)(rb + bo);
        acc[0][ct] = MFMA_F16(qh[0][kc], bh, acc[0][ct]);
        acc[1][ct] = MFMA_F16(qh[1][kc], bh, acc[1][ct]);
      }
    }
    __builtin_amdgcn_s_setprio(0);

    // ---- softmax, exp2 domain with deferred max (THR=24) + PV ----
    float vv[2][3];
#pragma unroll
    for (int ct=0;ct<2;ct++){
      int c = (nt*32 + ct*16 + lj)*3;
      vv[ct][0]=vlds[c]; vv[ct][1]=vlds[c+1]; vv[ct][2]=vlds[c+2];
    }
    float pm[2][4];
    float need = -1e30f;
#pragma unroll
    for (int rt=0;rt<2;rt++)
#pragma unroll
      for (int r=0;r<4;r++){
        pm[rt][r] = fmaxf(acc[rt][0][r], acc[rt][1][r]);
        need = fmaxf(need, pm[rt][r] - m[rt][r]);
      }
    if (need > 24.f){      // fires at tile 0 and rarely after: rescale
#pragma unroll
      for (int rt=0;rt<2;rt++)
#pragma unroll
        for (int r=0;r<4;r++){
          float mn = fmaxf(m[rt][r], pm[rt][r]);
          float sc = EXP2R(m[rt][r] - mn);
          ssum[rt][r] *= sc;
          o[rt][r][0] *= sc; o[rt][r][1] *= sc; o[rt][r][2] *= sc;
          m[rt][r] = mn;
        }
    }
#pragma unroll
    for (int rt=0;rt<2;rt++)
#pragma unroll
      for (int r=0;r<4;r++){
        float p0 = EXP2R(acc[rt][0][r] - m[rt][r]);
        float p1 = EXP2R(acc[rt][1][r] - m[rt][r]);
        ssum[rt][r] += p0 + p1;
        o[rt][r][0] += p0*vv[0][0] + p1*vv[1][0];
        o[rt][r][1] += p0*vv[0][1] + p1*vv[1][1];
        o[rt][r][2] += p0*vv[0][2] + p1*vv[1][2];
      }
  } // nt

  // ---- merge 16 lanes (lj) per row, write partial (m,s,o) ----
#pragma unroll
  for (int rt=0;rt<2;rt++)
#pragma unroll
    for (int r=0;r<4;r++){
      float mm = m[rt][r];
      mm = fmaxf(mm, __shfl_xor(mm,1));
      mm = fmaxf(mm, __shfl_xor(mm,2));
      mm = fmaxf(mm, __shfl_xor(mm,4));
      mm = fmaxf(mm, __shfl_xor(mm,8));
      float f = EXP2R(m[rt][r]-mm);
      float sl = ssum[rt][r]*f;
      float o0=o[rt][r][0]*f, o1=o[rt][r][1]*f, o2=o[rt][r][2]*f;
      sl += __shfl_xor(sl,1); sl += __shfl_xor(sl,2); sl += __shfl_xor(sl,4); sl += __shfl_xor(sl,8);
      o0 += __shfl_xor(o0,1); o0 += __shfl_xor(o0,2); o0 += __shfl_xor(o0,4); o0 += __shfl_xor(o0,8);
      o1 += __shfl_xor(o1,1); o1 += __shfl_xor(o1,2); o1 += __shfl_xor(o1,4); o1 += __shfl_xor(o1,8);
      o2 += __shfl_xor(o2,1); o2 += __shfl_xor(o2,2); o2 += __shfl_xor(o2,4); o2 += __shfl_xor(o2,8);
      if (lj == 0){
        int prow = qrow0 + rt*16 + lq*4 + r;
        float* pp = part + ((size_t)(s*6 + ks)*1024 + prow)*5;
        pp[0]=mm; pp[1]=sl; pp[2]=o0; pp[3]=o1; pp[4]=o2;
      }
    }
  #undef ISSUE_TILE
}

// merge 6 partials per q-row (4 K-parts, 2 M-parts) -> blended output
__global__ void kast_merge6(const float* __restrict__ part, float* __restrict__ OUT_){
  int r = blockIdx.x*256 + threadIdx.x;   // 0..57343
  if (r >= 56*1024) return;
  int s = r >> 10, row = r & 1023;
  const float* p[6];
#pragma unroll
  for (int i=0;i<6;i++) p[i] = part + ((size_t)(s*6+i)*1024 + row)*5;
  // K-attn: parts 0..3
  float M1 = fmaxf(fmaxf(p[0][0], p[1][0]), fmaxf(p[2][0], p[3][0]));
  float sK = 0.f, oK0 = 0.f, oK1 = 0.f, oK2 = 0.f;
#pragma unroll
  for (int i=0;i<4;i++){
    float e = EXP2R(p[i][0]-M1);
    sK += p[i][1]*e; oK0 += p[i][2]*e; oK1 += p[i][3]*e; oK2 += p[i][4]*e;
  }
  // M-attn: parts 4..5
  float M2 = fmaxf(p[4][0], p[5][0]);
  float e0 = EXP2R(p[4][0]-M2), e1 = EXP2R(p[5][0]-M2);
  float sM = p[4][1]*e0 + p[5][1]*e1;
  float w1 = 0.8f / sK;
  float w2 = 0.2f / sM;
  float* op = OUT_ + (size_t)(s*1024 + row)*3;
  op[0] = oK0*w1 + (p[4][2]*e0 + p[5][2]*e1)*w2;
  op[1] = oK1*w1 + (p[4][3]*e0 + p[5][3]*e1)*w2;
  op[2] = oK2*w1 + (p[4][4]*e0 + p[5][4]*e1)*w2;
}

// =====================================================================
// Fallback (round-2 passing kernel) if ws too small
// =====================================================================
__launch_bounds__(256, 2)
__global__ void kast_attn_fb(const float* __restrict__ K_, const float* __restrict__ V_,
                             const float* __restrict__ MK_, const float* __restrict__ MV_,
                             float* __restrict__ OUT_) {
  __shared__ char KhB[64*512];
  __shared__ char KlB[64*512];
  __shared__ float vlds[192];

  const int bid = blockIdx.x;
  const int s  = ((bid>>6)<<3) | (bid & 7);
  const int qb = (bid>>3) & 7;
  const int b = s / 7, t = s % 7;
  const float* qptr = K_ + (size_t)((b*8 + t + 1) * 1024) * 256;
  const float* k1   = K_ + (size_t)((b*8 + t) * 1024) * 256;
  const float* v1   = V_ + (size_t)((b*8 + t) * 1024) * 3;
  const float* k2   = MK_ + (size_t)((b*8 + t) * 512) * 256;
  const float* v2   = MV_ + (size_t)((b*8 + t) * 512) * 3;
  float* outp = OUT_ + (size_t)((b*7 + t) * 1024) * 3;

  const int tid = threadIdx.x;
  const int w = tid >> 6, l = tid & 63;
  const int lj = l & 15, lq = l >> 4;
  const int qrow0 = qb*128 + w*32;

  bf16x8 qh[2][8], ql[2][8];
#pragma unroll
  for (int rt=0; rt<2; rt++){
    const float* qr = qptr + (size_t)(qrow0 + rt*16 + lj)*256 + lq*8;
#pragma unroll
    for (int kc=0; kc<8; kc++){
      float4 a = *(const float4*)(qr + kc*32);
      float4 c = *(const float4*)(qr + kc*32 + 4);
      union { uint32_t d[4]; bf16x8 v; } hh, ll;
      split_pair(a.x, a.y, hh.d[0], ll.d[0]);
      split_pair(a.z, a.w, hh.d[1], ll.d[1]);
      split_pair(c.x, c.y, hh.d[2], ll.d[2]);
      split_pair(c.z, c.w, hh.d[3], ll.d[3]);
      qh[rt][kc]=hh.v; ql[rt][kc]=ll.v;
    }
  }

  for (int ph=0; ph<2; ph++){
    const float* ks = ph ? k2 : k1;
    const float* vs = ph ? v2 : v1;
    const int ntiles = ph ? 8 : 16;
    float m[2][4], ssum[2][4], o[2][4][3];
#pragma unroll
    for (int rt=0;rt<2;rt++)
#pragma unroll
      for (int r=0;r<4;r++){
        m[rt][r]=-1e30f; ssum[rt][r]=0.f;
        o[rt][r][0]=0.f; o[rt][r][1]=0.f; o[rt][r][2]=0.f;
      }

    for (int nt=0; nt<ntiles; nt++){
      __syncthreads();
      const float* kt = ks + (size_t)nt*64*256;
#pragma unroll 4
      for (int i=0;i<16;i++){
        int f4i = tid + i*256;
        int row = f4i >> 6;
        int col4 = f4i & 63;
        float4 x = *(const float4*)(kt + row*256 + col4*4);
        uint32_t hp0,lp0,hp1,lp1;
        split_pair(x.x,x.y,hp0,lp0);
        split_pair(x.z,x.w,hp1,lp1);
        int boff = row*512 + ((col4*8) ^ ((row&7)<<4));
        *(uint2*)(KhB + boff) = make_uint2(hp0,hp1);
        *(uint2*)(KlB + boff) = make_uint2(lp0,lp1);
      }
      if (tid < 192) vlds[tid] = vs[nt*192 + tid];
      __syncthreads();

      f32x4 acc[2][4];
#pragma unroll
      for (int rt=0;rt<2;rt++)
#pragma unroll
        for (int ct=0;ct<4;ct++)
          acc[rt][ct] = (f32x4){0.f,0.f,0.f,0.f};

      const int sx = (l&7)<<4;
#pragma unroll
      for (int ct=0;ct<4;ct++){
        const char* rbh = KhB + (ct*16 + lj)*512;
        const char* rbl = KlB + (ct*16 + lj)*512;
#pragma unroll
        for (int kc=0;kc<8;kc++){
          int bo = (kc*64 + (lq<<4)) ^ sx;
          bf16x8 bh = *(const bf16x8*)(rbh + bo);
          bf16x8 bl = *(const bf16x8*)(rbl + bo);
          acc[0][ct] = MFMA_BF16(qh[0][kc], bh, acc[0][ct]);
          acc[1][ct] = MFMA_BF16(qh[1][kc], bh, acc[1][ct]);
          acc[0][ct] = MFMA_BF16(qh[0][kc], bl, acc[0][ct]);
          acc[1][ct] = MFMA_BF16(qh[1][kc], bl, acc[1][ct]);
          acc[0][ct] = MFMA_BF16(ql[0][kc], bh, acc[0][ct]);
          acc[1][ct] = MFMA_BF16(ql[1][kc], bh, acc[1][ct]);
        }
      }

      float vv[4][3];
#pragma unroll
      for (int ct=0;ct<4;ct++){
        int c = (ct*16 + lj)*3;
        vv[ct][0]=vlds[c]; vv[ct][1]=vlds[c+1]; vv[ct][2]=vlds[c+2];
      }
#pragma unroll
      for (int rt=0;rt<2;rt++)
#pragma unroll
        for (int r=0;r<4;r++){
          float s0=acc[rt][0][r], s1=acc[rt][1][r], s2=acc[rt][2][r], s3=acc[rt][3][r];
          float tmax = fmaxf(fmaxf(s0,s1),fmaxf(s2,s3));
          float mo = m[rt][r];
          float mn = fmaxf(mo, tmax);
          float sc = __expf(mo - mn);
          float p0=__expf(s0-mn), p1=__expf(s1-mn), p2=__expf(s2-mn), p3=__expf(s3-mn);
          ssum[rt][r] = ssum[rt][r]*sc + ((p0+p1)+(p2+p3));
          o[rt][r][0] = o[rt][r][0]*sc + (p0*vv[0][0]+p1*vv[1][0]) + (p2*vv[2][0]+p3*vv[3][0]);
          o[rt][r][1] = o[rt][r][1]*sc + (p0*vv[0][1]+p1*vv[1][1]) + (p2*vv[2][1]+p3*vv[3][1]);
          o[rt][r][2] = o[rt][r][2]*sc + (p0*vv[0][2]+p1*vv[1][2]) + (p2*vv[2][2]+p3*vv[3][2]);
          m[rt][r]=mn;
        }
    }

    const float coef = ph ? 0.2f : 0.8f;
#pragma unroll
    for (int rt=0;rt<2;rt++)
#pragma unroll
      for (int r=0;r<4;r++){
        float mm = m[rt][r];
        mm = fmaxf(mm, __shfl_xor(mm,1));
        mm = fmaxf(mm, __shfl_xor(mm,2));
        mm = fmaxf(mm, __shfl_xor(mm,4));
        mm = fmaxf(mm, __shfl_xor(mm,8));
        float f = __expf(m[rt][r]-mm);
        float sl = ssum[rt][r]*f;
        float o0=o[rt][r][0]*f, o1=o[rt][r][1]*f, o2=o[rt][r][2]*f;
        sl += __shfl_xor(sl,1); sl += __shfl_xor(sl,2); sl += __shfl_xor(sl,4); sl += __shfl_xor(sl,8);
        o0 += __shfl_xor(o0,1); o0 += __shfl_xor(o0,2); o0 += __shfl_xor(o0,4); o0 += __shfl_xor(o0,8);
        o1 += __shfl_xor(o1,1); o1 += __shfl_xor(o1,2); o1 += __shfl_xor(o1,4); o1 += __shfl_xor(o1,8);
        o2 += __shfl_xor(o2,1); o2 += __shfl_xor(o2,2); o2 += __shfl_xor(o2,4); o2 += __shfl_xor(o2,8);
        if (lj == 0){
          int row = qrow0 + rt*16 + lq*4 + r;
          float* op = outp + (size_t)row*3;
          float invs = coef / sl;
          if (ph==0){ op[0]=o0*invs; op[1]=o1*invs; op[2]=o2*invs; }
          else      { op[0]+=o0*invs; op[1]+=o1*invs; op[2]+=o2*invs; }
        }
      }
  }
}

// ground truth = v[:,1:] (second output, exact copy)
__global__ void kast_gt(const float* __restrict__ V_, float* __restrict__ OUT_){
  int s = blockIdx.x; int b = s/7, t = s%7;
  const float4* src = (const float4*)(V_ + (size_t)(b*8+t+1)*3072);
  float4* dst = (float4*)(OUT_ + 172032 + (size_t)s*3072);
  for (int i=threadIdx.x; i<768; i+=256) dst[i] = src[i];
}

extern "C" void kernel_launch(void* const* d_in, const int* in_sizes, int n_in,
                              void* d_out, int out_size, void* d_ws, size_t ws_size,
                              hipStream_t stream) {
  (void)in_sizes; (void)n_in; (void)out_size;
  const float* K_  = (const float*)d_in[0];
  const float* V_  = (const float*)d_in[1];
  const float* MK_ = (const float*)d_in[2];
  const float* MV_ = (const float*)d_in[3];
  float* out = (float*)d_out;

  // ws layout (bytes): khi 33.55M | mkhi 16.78M | partials 6.88M
  const size_t NEED = 57212928;
  if (ws_size >= NEED){
    uint8_t* w8 = (uint8_t*)d_ws;
    ushort* khi  = (ushort*)(w8);
    ushort* mkhi = (ushort*)(w8 + 33554432);
    float*  part = (float*)(w8 + 50331648);
    hipLaunchKernelGGL(kast_cvt3, dim3(12288), dim3(256), 0, stream, K_, MK_,
                       (uint4*)khi, (uint4*)mkhi);
    hipLaunchKernelGGL(kast_attn16, dim3(2688), dim3(256), 0, stream, khi, mkhi, V_, MV_, part);
    hipLaunchKernelGGL(kast_merge6, dim3(224),  dim3(256), 0, stream, part, out);
  } else {
    hipLaunchKernelGGL(kast_attn_fb, dim3(448), dim3(256), 0, stream, K_, V_, MK_, MV_, out);
  }
  hipLaunchKernelGGL(kast_gt, dim3(56), dim3(256), 0, stream, V_, out);
}